// Round 4
// baseline (290.877 us; speedup 1.0000x reference)
//
#include <hip/hip_runtime.h>

#define T_STEPS 65536
#define NZ 64
#define NH1 128
#define NH2 64
#define NEDGE 512
#define NCHUNK 8192
#define CL 8            // timesteps per chunk (T_STEPS / NCHUNK)
#define NSUPER 128
#define SUP_L 64        // chunks per super (NCHUNK / NSUPER)

// ---- ws layout (bytes). Base need = 33,694,720 (== round-3 proven size)
#define ADJ_OFF        0          // 64 * u64
#define BASE1_OFF      512        // 128 * f64
#define W1T_OFF        1536       // 128 * f64
#define NBRT_OFF       2560       // 64*64 u8, transposed [k][z]
#define MAXDEG_OFF     6656       // i32
#define CHUNKSTATE_OFF 6720       // NCHUNK * i32 = 32768 (ends 39488)
#define W2D_OFF        40960      // 128*64 f64 = 65536  ([h][j])
#define W3D_OFF        106496     // 64*64 f64 = 32768   ([j][z])
#define B2D_OFF        139264     // 64 f64
#define B3D_OFF        139776     // 64 f64
#define LG64_OFF       140288     // 64*T f64 (z-major: lg64[z*T + t]) = 32MB
#define FTAB_OFF       (LG64_OFF + (size_t)T_STEPS * NZ * 8)   // T*64 u8 = 4MB (optional)
#define WS_NEED_FTAB   (FTAB_OFF + (size_t)T_STEPS * NZ)

// ---- d_out used as scratch before finalize overwrites it (deterministic)
#define CHUNKG_DOUT    0          // NCHUNK*64 u8 = 524288
#define SUPERS_DOUT    524288     // NSUPER*64 u8 = 8192
#define SUPSTATE_DOUT  532480     // NSUPER * i32 = 512

typedef unsigned long long ull;

// ---------------------------------------------------------------------------
// K1: adjacency bitmasks, padded neighbor lists, f64 weight precompute.
// ---------------------------------------------------------------------------
__global__ void prep_kernel(const float* __restrict__ pa,
                            const int* __restrict__ edges,
                            const float* __restrict__ W1,
                            const float* __restrict__ b1,
                            const float* __restrict__ W2,
                            const float* __restrict__ b2,
                            const float* __restrict__ W3,
                            const float* __restrict__ b3,
                            unsigned char* ws) {
  ull* adj = (ull*)(ws + ADJ_OFF);
  double* base1 = (double*)(ws + BASE1_OFF);
  double* w1t   = (double*)(ws + W1T_OFF);
  unsigned char* nbrT = ws + NBRT_OFF;
  double* W2d = (double*)(ws + W2D_OFF);
  double* W3d = (double*)(ws + W3D_OFF);
  double* b2d = (double*)(ws + B2D_OFF);
  double* b3d = (double*)(ws + B3D_OFF);
  __shared__ int smax;
  __shared__ int sdeg[NZ];
  int tid = threadIdx.x;
  if (tid == 0) smax = 0;
  if (tid < NZ) adj[tid] = 0ull;
  __syncthreads();
  if (tid < NEDGE) {
    int e0 = edges[tid];
    int e1 = edges[NEDGE + tid];
    atomicOr(&adj[e0], 1ull << e1);
    atomicOr(&adj[e1], 1ull << e0);
  }
  if (tid < NZ) atomicOr(&adj[tid], 1ull << tid);  // self loops
  if (tid < NH1) {
    double acc = (double)b1[tid];
    for (int d = 0; d < 64; ++d)
      acc += (double)pa[d] * (double)W1[d * NH1 + tid];
    base1[tid] = acc;
    w1t[tid] = (double)W1[64 * NH1 + tid];
  }
  for (int i = tid; i < NH1 * NH2; i += 512) W2d[i] = (double)W2[i];
  for (int i = tid; i < NH2 * NZ; i += 512)  W3d[i] = (double)W3[i];
  if (tid < NH2) b2d[tid] = (double)b2[tid];
  if (tid < NZ)  b3d[tid] = (double)b3[tid];
  __syncthreads();
  if (tid < NZ) {
    ull m = adj[tid];
    int deg = 0;
    while (m) {
      int j = __builtin_ctzll(m);
      m &= m - 1;
      nbrT[deg * 64 + tid] = (unsigned char)j;
      ++deg;
    }
    sdeg[tid] = deg;
    atomicMax(&smax, deg);
  }
  __syncthreads();
  if (tid < NZ) {
    int deg = sdeg[tid];
    unsigned char j0 = nbrT[0 * 64 + tid];  // deg >= 1 (self loop)
    for (int k = deg; k < smax; ++k) nbrT[k * 64 + tid] = j0;
  }
  if (tid == 0) *(int*)(ws + MAXDEG_OFF) = smax;
}

// ---------------------------------------------------------------------------
// K2: j-split MLP. Block = 4 waves over the SAME 64 timesteps (lane = t).
// Wave w computes h2[j] for j in [16w,16w+16) (acc[16] in VGPRs), exchanges
// via a [j][t] LDS tile (conflict-free), then computes logits z in
// [16w,16w+16) and stores z-major coalesced. No transpose tile needed.
// ---------------------------------------------------------------------------
__global__ __launch_bounds__(256) void mlp_kernel(
    const float* __restrict__ times,
    const unsigned char* __restrict__ ws_ro,
    double* __restrict__ lg64) {
  __shared__ double h2lds[64][64];  // [j][t] 32KB
  const double* __restrict__ base1 = (const double*)(ws_ro + BASE1_OFF);
  const double* __restrict__ w1t   = (const double*)(ws_ro + W1T_OFF);
  const double* __restrict__ W2d   = (const double*)(ws_ro + W2D_OFF);
  const double* __restrict__ W3d   = (const double*)(ws_ro + W3D_OFF);
  const double* __restrict__ b2d   = (const double*)(ws_ro + B2D_OFF);
  const double* __restrict__ b3d   = (const double*)(ws_ro + B3D_OFF);

  int tid = threadIdx.x, lane = tid & 63, wv = tid >> 6;
  int j0 = wv * 16;
  int t0 = blockIdx.x * 64;
  double tv = (double)times[t0 + lane];

  double acc[16];
  #pragma unroll
  for (int jj = 0; jj < 16; ++jj) acc[jj] = b2d[j0 + jj];

  #pragma unroll 4
  for (int h = 0; h < NH1; ++h) {
    double a = fma(tv, w1t[h], base1[h]);
    a = a > 0.0 ? a : 0.0;
    const double* __restrict__ row = W2d + h * 64 + j0;
    #pragma unroll
    for (int jj = 0; jj < 16; ++jj) acc[jj] = fma(a, row[jj], acc[jj]);
  }
  #pragma unroll
  for (int jj = 0; jj < 16; ++jj)
    h2lds[j0 + jj][lane] = acc[jj] > 0.0 ? acc[jj] : 0.0;
  __syncthreads();

  double lg[16];
  #pragma unroll
  for (int zz = 0; zz < 16; ++zz) lg[zz] = b3d[j0 + zz];
  #pragma unroll 4
  for (int j = 0; j < 64; ++j) {
    double hv = h2lds[j][lane];
    const double* __restrict__ row = W3d + j * 64 + j0;
    #pragma unroll
    for (int zz = 0; zz < 16; ++zz) lg[zz] = fma(hv, row[zz], lg[zz]);
  }
  #pragma unroll
  for (int zz = 0; zz < 16; ++zz)
    lg64[(size_t)(j0 + zz) * T_STEPS + t0 + lane] = lg[zz];
}

// ---------------------------------------------------------------------------
// K3: per-chunk composed transition tables; also emits per-step F tables
// (if ftab != null) so finalize can skip the argmax butterfly.
// ---------------------------------------------------------------------------
__global__ __launch_bounds__(256) void chunk_tables_kernel(
    const double* __restrict__ lg64, const unsigned char* __restrict__ ws_ro,
    unsigned char* __restrict__ chunkG, unsigned char* __restrict__ ftab) {
  __shared__ double lgs[4][CL][64];
  __shared__ unsigned char nbrTs[4096];
  int tid = threadIdx.x, lane = tid & 63, wv = tid >> 6;
  for (int i = tid; i < 1024; i += 256)
    ((unsigned int*)nbrTs)[i] = ((const unsigned int*)(ws_ro + NBRT_OFF))[i];
  const int maxdeg = *(const int*)(ws_ro + MAXDEG_OFF);
  ull mask = ((const ull*)(ws_ro + ADJ_OFF))[lane];
  int c = blockIdx.x * 4 + wv;
  double lg[CL];
  #pragma unroll
  for (int i = 0; i < CL; ++i)
    lg[i] = lg64[(size_t)lane * T_STEPS + c * CL + i];  // 64B contig per lane
  #pragma unroll
  for (int i = 0; i < CL; ++i) lgs[wv][i][lane] = lg[i];
  __syncthreads();

  double vn[CL];
  int jn[CL];
  #pragma unroll
  for (int i = 0; i < CL; ++i) { vn[i] = -1.0e300; jn[i] = 0; }
  #pragma unroll 2
  for (int k = 0; k < maxdeg; ++k) {
    int j = nbrTs[k * 64 + lane];
    #pragma unroll
    for (int i = 0; i < CL; ++i) {
      double val = lgs[wv][i][j];
      if (val > vn[i]) { vn[i] = val; jn[i] = j; }  // ascending j, strict >
    }
  }

  int F[CL];
  #pragma unroll
  for (int i = 0; i < CL; ++i) {
    double v = lg[i];
    int idx = lane;
    #pragma unroll
    for (int off = 1; off < 64; off <<= 1) {
      double ov = __shfl_xor(v, off, 64);
      int oi = __shfl_xor(idx, off, 64);
      if (ov > v || (ov == v && oi < idx)) { v = ov; idx = oi; }
    }
    int f;
    if ((mask >> idx) & 1ull) f = idx;
    else {
      double vg = v - 1.0;
      if (vn[i] > vg) f = jn[i];
      else if (vn[i] < vg) f = idx;
      else f = jn[i] < idx ? jn[i] : idx;
    }
    F[i] = f;
  }
  if (ftab) {
    #pragma unroll
    for (int i = 0; i < CL; ++i)
      ftab[(size_t)(c * CL + i) * 64 + lane] = (unsigned char)F[i];
  }
  int cur = lane;
  #pragma unroll
  for (int i = 0; i < CL; ++i) cur = __shfl(F[i], cur, 64);
  chunkG[(size_t)c * 64 + lane] = (unsigned char)cur;
}

// ---------------------------------------------------------------------------
// K4: compose SUP_L chunk tables into each super table.
// ---------------------------------------------------------------------------
__global__ void super_compose_kernel(const unsigned char* __restrict__ chunkG,
                                     unsigned char* __restrict__ superS) {
  int lane = threadIdx.x & 63, wv = threadIdx.x >> 6;
  int k = blockIdx.x * 4 + wv;
  int cur = lane;
  #pragma unroll 8
  for (int c = k * SUP_L; c < (k + 1) * SUP_L; ++c) {
    int g = chunkG[(size_t)c * 64 + lane];
    cur = __shfl(g, cur, 64);
  }
  superS[(size_t)k * 64 + lane] = (unsigned char)cur;
}

// ---------------------------------------------------------------------------
// K5: sequential walk over NSUPER super tables (1 wave, LDS-staged).
// ---------------------------------------------------------------------------
__global__ void super_walk_kernel(const unsigned char* __restrict__ superS,
                                  int* __restrict__ supState) {
  __shared__ unsigned char ssup[NSUPER * 64];
  int lane = threadIdx.x;
  for (int i = lane; i < NSUPER * 16; i += 64)
    ((unsigned int*)ssup)[i] = ((const unsigned int*)superS)[i];
  __syncthreads();
  int s = 0;
  if (lane == 0) supState[0] = 0;
  for (int k = 0; k < NSUPER; ++k) {
    int v = ssup[k * 64 + lane];
    s = __shfl(v, s, 64);
    if (lane == 0 && k + 1 < NSUPER) supState[k + 1] = s;
  }
}

// ---------------------------------------------------------------------------
// K6: per-chunk start states — LDS-staged walk.
// ---------------------------------------------------------------------------
__global__ __launch_bounds__(256) void chunk_states_kernel(
    const unsigned char* __restrict__ chunkG,
    const int* __restrict__ supState,
    int* __restrict__ chunkState) {
  __shared__ unsigned char g[4][SUP_L * 64];
  __shared__ int sbuf[4][SUP_L];
  int tid = threadIdx.x, lane = tid & 63, wv = tid >> 6;
  int k = blockIdx.x * 4 + wv;
  const unsigned int* src = (const unsigned int*)(chunkG + (size_t)k * SUP_L * 64);
  unsigned int* dst = (unsigned int*)g[wv];
  #pragma unroll 4
  for (int i = lane; i < SUP_L * 16; i += 64) dst[i] = src[i];
  int s = supState[k];
  for (int c = 0; c < SUP_L; ++c) {
    if (lane == 0) sbuf[wv][c] = s;
    s = g[wv][c * 64 + s];
  }
  chunkState[k * SUP_L + lane] = sbuf[wv][lane];
}

// ---------------------------------------------------------------------------
// K7: finalize. If ftab != null: streaming — LDS-staged F lookups, no
// butterfly. Else: fallback f64 shfl-argmax walk (round-3 semantics).
// ---------------------------------------------------------------------------
__global__ __launch_bounds__(256) void finalize_kernel(
    const double* __restrict__ lg64, const unsigned char* __restrict__ ws_ro,
    const int* __restrict__ chunkState, const unsigned char* __restrict__ ftab,
    float* __restrict__ out) {
  __shared__ ull adjs[64];
  __shared__ unsigned char fstage[4][CL * 64];
  int tid = threadIdx.x, lane = tid & 63, wv = tid >> 6;
  if (tid < 64) adjs[tid] = ((const ull*)(ws_ro + ADJ_OFF))[tid];
  __syncthreads();
  int c = blockIdx.x * 4 + wv;
  int s = chunkState[c];
  size_t tb = (size_t)c * CL * 64;

  double lgv[CL];
  #pragma unroll
  for (int i = 0; i < CL; ++i)
    lgv[i] = lg64[(size_t)lane * T_STEPS + c * CL + i];  // 64B contig per lane

  if (ftab) {
    unsigned int* dst = (unsigned int*)fstage[wv];
    const unsigned int* src = (const unsigned int*)(ftab + tb);
    #pragma unroll
    for (int i = lane; i < CL * 16; i += 64) dst[i] = src[i];
    // wave-private LDS; compiler inserts the lgkm wait
    #pragma unroll
    for (int i = 0; i < CL; ++i) {
      int bit = (int)((adjs[s] >> lane) & 1ull);
      out[tb + i * 64 + lane] = (float)(bit ? lgv[i] : lgv[i] - 1.0);
      s = fstage[wv][i * 64 + s];  // uniform broadcast read
    }
  } else {
    #pragma unroll
    for (int i = 0; i < CL; ++i) {
      int bit = (int)((adjs[s] >> lane) & 1ull);
      double v = bit ? lgv[i] : lgv[i] - 1.0;
      out[tb + i * 64 + lane] = (float)v;
      int idx = lane;
      #pragma unroll
      for (int off = 1; off < 64; off <<= 1) {
        double ov = __shfl_xor(v, off, 64);
        int oi = __shfl_xor(idx, off, 64);
        if (ov > v || (ov == v && oi < idx)) { v = ov; idx = oi; }
      }
      s = idx;
    }
  }
}

// ---------------------------------------------------------------------------
extern "C" void kernel_launch(void* const* d_in, const int* in_sizes, int n_in,
                              void* d_out, int out_size, void* d_ws, size_t ws_size,
                              hipStream_t stream) {
  const float* pa    = (const float*)d_in[0];
  const float* times = (const float*)d_in[1];
  // d_in[2] zone_features: unused by the reference
  const int*   edges = (const int*)d_in[3];
  const float* W1    = (const float*)d_in[4];
  const float* b1    = (const float*)d_in[5];
  const float* W2    = (const float*)d_in[6];
  const float* b2    = (const float*)d_in[7];
  const float* W3    = (const float*)d_in[8];
  const float* b3    = (const float*)d_in[9];

  unsigned char* ws = (unsigned char*)d_ws;
  unsigned char* outb = (unsigned char*)d_out;  // scratch until finalize
  double* lg64 = (double*)(ws + LG64_OFF);
  unsigned char* ftab = (ws_size >= WS_NEED_FTAB) ? (ws + FTAB_OFF) : nullptr;
  unsigned char* chunkG = outb + CHUNKG_DOUT;
  unsigned char* superS = outb + SUPERS_DOUT;
  int* supState = (int*)(outb + SUPSTATE_DOUT);
  int* chunkState = (int*)(ws + CHUNKSTATE_OFF);

  hipLaunchKernelGGL(prep_kernel, dim3(1), dim3(512), 0, stream,
                     pa, edges, W1, b1, W2, b2, W3, b3, ws);
  hipLaunchKernelGGL(mlp_kernel, dim3(T_STEPS / 64), dim3(256), 0, stream,
                     times, ws, lg64);
  hipLaunchKernelGGL(chunk_tables_kernel, dim3(NCHUNK / 4), dim3(256), 0, stream,
                     lg64, ws, chunkG, ftab);
  hipLaunchKernelGGL(super_compose_kernel, dim3(NSUPER / 4), dim3(256), 0, stream,
                     chunkG, superS);
  hipLaunchKernelGGL(super_walk_kernel, dim3(1), dim3(64), 0, stream,
                     superS, supState);
  hipLaunchKernelGGL(chunk_states_kernel, dim3(NSUPER / 4), dim3(256), 0, stream,
                     chunkG, supState, chunkState);
  hipLaunchKernelGGL(finalize_kernel, dim3(NCHUNK / 4), dim3(256), 0, stream,
                     lg64, ws, chunkState, ftab, (float*)d_out);
}

// Round 5
// 152.994 us; speedup vs baseline: 1.9012x; 1.9012x over previous
//
#include <hip/hip_runtime.h>

#define T_STEPS 65536
#define NZ 64
#define NH1 128
#define NH2 64
#define NEDGE 512
#define NCHUNK 8192
#define CL 8            // timesteps per chunk (T_STEPS / NCHUNK)
#define NSUPER 128
#define SUP_L 64        // chunks per super (NCHUNK / NSUPER)

// ---- ws layout (bytes). Base need = 33,694,720 (== round-3 proven size)
#define ADJ_OFF        0          // 64 * u64
#define BASE1_OFF      512        // 128 * f64
#define W1T_OFF        1536       // 128 * f64
#define NBRT_OFF       2560       // 64*64 u8, transposed [k][z]
#define MAXDEG_OFF     6656       // i32
#define CHUNKSTATE_OFF 6720       // NCHUNK * i32 = 32768 (ends 39488)
#define W2D_OFF        40960      // 128*64 f64 = 65536  ([h][j])
#define W3D_OFF        106496     // 64*64 f64 = 32768   ([j][z])
#define B2D_OFF        139264     // 64 f64
#define B3D_OFF        139776     // 64 f64
#define LG64_OFF       140288     // 64*T f64 (z-major: lg64[z*T + t]) = 32MB
#define FTAB_OFF       (LG64_OFF + (size_t)T_STEPS * NZ * 8)   // T*64 u8 = 4MB (optional)
#define WS_NEED_FTAB   (FTAB_OFF + (size_t)T_STEPS * NZ)

// ---- d_out used as scratch before finalize overwrites it (deterministic)
#define CHUNKG_DOUT    0          // NCHUNK*64 u8 = 524288
#define SUPERS_DOUT    524288     // NSUPER*64 u8 = 8192
#define SUPSTATE_DOUT  532480     // NSUPER * i32 = 512

typedef unsigned long long ull;

// ---------------------------------------------------------------------------
// K1: adjacency bitmasks, padded neighbor lists, f64 weight precompute.
// ---------------------------------------------------------------------------
__global__ void prep_kernel(const float* __restrict__ pa,
                            const int* __restrict__ edges,
                            const float* __restrict__ W1,
                            const float* __restrict__ b1,
                            const float* __restrict__ W2,
                            const float* __restrict__ b2,
                            const float* __restrict__ W3,
                            const float* __restrict__ b3,
                            unsigned char* ws) {
  ull* adj = (ull*)(ws + ADJ_OFF);
  double* base1 = (double*)(ws + BASE1_OFF);
  double* w1t   = (double*)(ws + W1T_OFF);
  unsigned char* nbrT = ws + NBRT_OFF;
  double* W2d = (double*)(ws + W2D_OFF);
  double* W3d = (double*)(ws + W3D_OFF);
  double* b2d = (double*)(ws + B2D_OFF);
  double* b3d = (double*)(ws + B3D_OFF);
  __shared__ int smax;
  __shared__ int sdeg[NZ];
  int tid = threadIdx.x;
  if (tid == 0) smax = 0;
  if (tid < NZ) adj[tid] = 0ull;
  __syncthreads();
  if (tid < NEDGE) {
    int e0 = edges[tid];
    int e1 = edges[NEDGE + tid];
    atomicOr(&adj[e0], 1ull << e1);
    atomicOr(&adj[e1], 1ull << e0);
  }
  if (tid < NZ) atomicOr(&adj[tid], 1ull << tid);  // self loops
  if (tid < NH1) {
    double acc = (double)b1[tid];
    for (int d = 0; d < 64; ++d)
      acc += (double)pa[d] * (double)W1[d * NH1 + tid];
    base1[tid] = acc;
    w1t[tid] = (double)W1[64 * NH1 + tid];
  }
  for (int i = tid; i < NH1 * NH2; i += 512) W2d[i] = (double)W2[i];
  for (int i = tid; i < NH2 * NZ; i += 512)  W3d[i] = (double)W3[i];
  if (tid < NH2) b2d[tid] = (double)b2[tid];
  if (tid < NZ)  b3d[tid] = (double)b3[tid];
  __syncthreads();
  if (tid < NZ) {
    ull m = adj[tid];
    int deg = 0;
    while (m) {
      int j = __builtin_ctzll(m);
      m &= m - 1;
      nbrT[deg * 64 + tid] = (unsigned char)j;
      ++deg;
    }
    sdeg[tid] = deg;
    atomicMax(&smax, deg);
  }
  __syncthreads();
  if (tid < NZ) {
    int deg = sdeg[tid];
    unsigned char j0 = nbrT[0 * 64 + tid];  // deg >= 1 (self loop)
    for (int k = deg; k < smax; ++k) nbrT[k * 64 + tid] = j0;
  }
  if (tid == 0) *(int*)(ws + MAXDEG_OFF) = smax;
}

// ---------------------------------------------------------------------------
// K2: j-split MLP. Block = 4 waves over the SAME 64 timesteps (lane = t).
// Wave w computes h2[j] for j in [16w,16w+16) (acc[16] in VGPRs). j0 is
// forced into an SGPR via readfirstlane so all weight reads are provably
// wave-uniform -> s_load streams (round-3 memory path) at round-4
// occupancy (4096 waves, 4/SIMD). h2 exchanged via [j][t] LDS tile;
// logits stored z-major coalesced.
// ---------------------------------------------------------------------------
__global__ __launch_bounds__(256) void mlp_kernel(
    const float* __restrict__ times,
    const unsigned char* __restrict__ ws_ro,
    double* __restrict__ lg64) {
  __shared__ double h2lds[64][64];  // [j][t] 32KB
  const double* __restrict__ base1 = (const double*)(ws_ro + BASE1_OFF);
  const double* __restrict__ w1t   = (const double*)(ws_ro + W1T_OFF);
  const double* __restrict__ W2d   = (const double*)(ws_ro + W2D_OFF);
  const double* __restrict__ W3d   = (const double*)(ws_ro + W3D_OFF);
  const double* __restrict__ b2d   = (const double*)(ws_ro + B2D_OFF);
  const double* __restrict__ b3d   = (const double*)(ws_ro + B3D_OFF);

  int tid = threadIdx.x, lane = tid & 63;
  // wave-uniform j-quarter, forced into SGPR so weight loads scalarize
  int j0 = __builtin_amdgcn_readfirstlane((tid >> 6) << 4);
  int t0 = blockIdx.x * 64;
  double tv = (double)times[t0 + lane];

  double acc[16];
  #pragma unroll
  for (int jj = 0; jj < 16; ++jj) acc[jj] = b2d[j0 + jj];

  #pragma unroll 2
  for (int h = 0; h < NH1; ++h) {
    double a = fma(tv, w1t[h], base1[h]);
    a = a > 0.0 ? a : 0.0;
    const double* __restrict__ row = W2d + h * 64 + j0;
    #pragma unroll
    for (int jj = 0; jj < 16; ++jj) acc[jj] = fma(a, row[jj], acc[jj]);
  }
  #pragma unroll
  for (int jj = 0; jj < 16; ++jj)
    h2lds[j0 + jj][lane] = acc[jj] > 0.0 ? acc[jj] : 0.0;
  __syncthreads();

  double lg[16];
  #pragma unroll
  for (int zz = 0; zz < 16; ++zz) lg[zz] = b3d[j0 + zz];
  #pragma unroll 2
  for (int j = 0; j < 64; ++j) {
    double hv = h2lds[j][lane];
    const double* __restrict__ row = W3d + j * 64 + j0;
    #pragma unroll
    for (int zz = 0; zz < 16; ++zz) lg[zz] = fma(hv, row[zz], lg[zz]);
  }
  #pragma unroll
  for (int zz = 0; zz < 16; ++zz)
    lg64[(size_t)(j0 + zz) * T_STEPS + t0 + lane] = lg[zz];
}

// ---------------------------------------------------------------------------
// K3: per-chunk composed transition tables; also emits per-step F tables
// (if ftab != null) so finalize can skip the argmax butterfly.
// ---------------------------------------------------------------------------
__global__ __launch_bounds__(256) void chunk_tables_kernel(
    const double* __restrict__ lg64, const unsigned char* __restrict__ ws_ro,
    unsigned char* __restrict__ chunkG, unsigned char* __restrict__ ftab) {
  __shared__ double lgs[4][CL][64];
  __shared__ unsigned char nbrTs[4096];
  int tid = threadIdx.x, lane = tid & 63, wv = tid >> 6;
  for (int i = tid; i < 1024; i += 256)
    ((unsigned int*)nbrTs)[i] = ((const unsigned int*)(ws_ro + NBRT_OFF))[i];
  const int maxdeg = *(const int*)(ws_ro + MAXDEG_OFF);
  ull mask = ((const ull*)(ws_ro + ADJ_OFF))[lane];
  int c = blockIdx.x * 4 + wv;
  double lg[CL];
  #pragma unroll
  for (int i = 0; i < CL; ++i)
    lg[i] = lg64[(size_t)lane * T_STEPS + c * CL + i];  // 64B contig per lane
  #pragma unroll
  for (int i = 0; i < CL; ++i) lgs[wv][i][lane] = lg[i];
  __syncthreads();

  double vn[CL];
  int jn[CL];
  #pragma unroll
  for (int i = 0; i < CL; ++i) { vn[i] = -1.0e300; jn[i] = 0; }
  #pragma unroll 2
  for (int k = 0; k < maxdeg; ++k) {
    int j = nbrTs[k * 64 + lane];
    #pragma unroll
    for (int i = 0; i < CL; ++i) {
      double val = lgs[wv][i][j];
      if (val > vn[i]) { vn[i] = val; jn[i] = j; }  // ascending j, strict >
    }
  }

  int F[CL];
  #pragma unroll
  for (int i = 0; i < CL; ++i) {
    double v = lg[i];
    int idx = lane;
    #pragma unroll
    for (int off = 1; off < 64; off <<= 1) {
      double ov = __shfl_xor(v, off, 64);
      int oi = __shfl_xor(idx, off, 64);
      if (ov > v || (ov == v && oi < idx)) { v = ov; idx = oi; }
    }
    int f;
    if ((mask >> idx) & 1ull) f = idx;
    else {
      double vg = v - 1.0;
      if (vn[i] > vg) f = jn[i];
      else if (vn[i] < vg) f = idx;
      else f = jn[i] < idx ? jn[i] : idx;
    }
    F[i] = f;
  }
  if (ftab) {
    #pragma unroll
    for (int i = 0; i < CL; ++i)
      ftab[(size_t)(c * CL + i) * 64 + lane] = (unsigned char)F[i];
  }
  int cur = lane;
  #pragma unroll
  for (int i = 0; i < CL; ++i) cur = __shfl(F[i], cur, 64);
  chunkG[(size_t)c * 64 + lane] = (unsigned char)cur;
}

// ---------------------------------------------------------------------------
// K4: compose SUP_L chunk tables into each super table.
// ---------------------------------------------------------------------------
__global__ void super_compose_kernel(const unsigned char* __restrict__ chunkG,
                                     unsigned char* __restrict__ superS) {
  int lane = threadIdx.x & 63, wv = threadIdx.x >> 6;
  int k = blockIdx.x * 4 + wv;
  int cur = lane;
  #pragma unroll 8
  for (int c = k * SUP_L; c < (k + 1) * SUP_L; ++c) {
    int g = chunkG[(size_t)c * 64 + lane];
    cur = __shfl(g, cur, 64);
  }
  superS[(size_t)k * 64 + lane] = (unsigned char)cur;
}

// ---------------------------------------------------------------------------
// K5: sequential walk over NSUPER super tables (1 wave, LDS-staged).
// ---------------------------------------------------------------------------
__global__ void super_walk_kernel(const unsigned char* __restrict__ superS,
                                  int* __restrict__ supState) {
  __shared__ unsigned char ssup[NSUPER * 64];
  int lane = threadIdx.x;
  for (int i = lane; i < NSUPER * 16; i += 64)
    ((unsigned int*)ssup)[i] = ((const unsigned int*)superS)[i];
  __syncthreads();
  int s = 0;
  if (lane == 0) supState[0] = 0;
  for (int k = 0; k < NSUPER; ++k) {
    int v = ssup[k * 64 + lane];
    s = __shfl(v, s, 64);
    if (lane == 0 && k + 1 < NSUPER) supState[k + 1] = s;
  }
}

// ---------------------------------------------------------------------------
// K6: per-chunk start states — LDS-staged walk.
// ---------------------------------------------------------------------------
__global__ __launch_bounds__(256) void chunk_states_kernel(
    const unsigned char* __restrict__ chunkG,
    const int* __restrict__ supState,
    int* __restrict__ chunkState) {
  __shared__ unsigned char g[4][SUP_L * 64];
  __shared__ int sbuf[4][SUP_L];
  int tid = threadIdx.x, lane = tid & 63, wv = tid >> 6;
  int k = blockIdx.x * 4 + wv;
  const unsigned int* src = (const unsigned int*)(chunkG + (size_t)k * SUP_L * 64);
  unsigned int* dst = (unsigned int*)g[wv];
  #pragma unroll 4
  for (int i = lane; i < SUP_L * 16; i += 64) dst[i] = src[i];
  int s = supState[k];
  for (int c = 0; c < SUP_L; ++c) {
    if (lane == 0) sbuf[wv][c] = s;
    s = g[wv][c * 64 + s];
  }
  chunkState[k * SUP_L + lane] = sbuf[wv][lane];
}

// ---------------------------------------------------------------------------
// K7: finalize. If ftab != null: streaming — LDS-staged F lookups, no
// butterfly. Else: fallback f64 shfl-argmax walk.
// ---------------------------------------------------------------------------
__global__ __launch_bounds__(256) void finalize_kernel(
    const double* __restrict__ lg64, const unsigned char* __restrict__ ws_ro,
    const int* __restrict__ chunkState, const unsigned char* __restrict__ ftab,
    float* __restrict__ out) {
  __shared__ ull adjs[64];
  __shared__ unsigned char fstage[4][CL * 64];
  int tid = threadIdx.x, lane = tid & 63, wv = tid >> 6;
  if (tid < 64) adjs[tid] = ((const ull*)(ws_ro + ADJ_OFF))[tid];
  __syncthreads();
  int c = blockIdx.x * 4 + wv;
  int s = chunkState[c];
  size_t tb = (size_t)c * CL * 64;

  double lgv[CL];
  #pragma unroll
  for (int i = 0; i < CL; ++i)
    lgv[i] = lg64[(size_t)lane * T_STEPS + c * CL + i];  // 64B contig per lane

  if (ftab) {
    unsigned int* dst = (unsigned int*)fstage[wv];
    const unsigned int* src = (const unsigned int*)(ftab + tb);
    #pragma unroll
    for (int i = lane; i < CL * 16; i += 64) dst[i] = src[i];
    // wave-private LDS; compiler inserts the lgkm wait
    #pragma unroll
    for (int i = 0; i < CL; ++i) {
      int bit = (int)((adjs[s] >> lane) & 1ull);
      out[tb + i * 64 + lane] = (float)(bit ? lgv[i] : lgv[i] - 1.0);
      s = fstage[wv][i * 64 + s];  // uniform broadcast read
    }
  } else {
    #pragma unroll
    for (int i = 0; i < CL; ++i) {
      int bit = (int)((adjs[s] >> lane) & 1ull);
      double v = bit ? lgv[i] : lgv[i] - 1.0;
      out[tb + i * 64 + lane] = (float)v;
      int idx = lane;
      #pragma unroll
      for (int off = 1; off < 64; off <<= 1) {
        double ov = __shfl_xor(v, off, 64);
        int oi = __shfl_xor(idx, off, 64);
        if (ov > v || (ov == v && oi < idx)) { v = ov; idx = oi; }
      }
      s = idx;
    }
  }
}

// ---------------------------------------------------------------------------
extern "C" void kernel_launch(void* const* d_in, const int* in_sizes, int n_in,
                              void* d_out, int out_size, void* d_ws, size_t ws_size,
                              hipStream_t stream) {
  const float* pa    = (const float*)d_in[0];
  const float* times = (const float*)d_in[1];
  // d_in[2] zone_features: unused by the reference
  const int*   edges = (const int*)d_in[3];
  const float* W1    = (const float*)d_in[4];
  const float* b1    = (const float*)d_in[5];
  const float* W2    = (const float*)d_in[6];
  const float* b2    = (const float*)d_in[7];
  const float* W3    = (const float*)d_in[8];
  const float* b3    = (const float*)d_in[9];

  unsigned char* ws = (unsigned char*)d_ws;
  unsigned char* outb = (unsigned char*)d_out;  // scratch until finalize
  double* lg64 = (double*)(ws + LG64_OFF);
  unsigned char* ftab = (ws_size >= WS_NEED_FTAB) ? (ws + FTAB_OFF) : nullptr;
  unsigned char* chunkG = outb + CHUNKG_DOUT;
  unsigned char* superS = outb + SUPERS_DOUT;
  int* supState = (int*)(outb + SUPSTATE_DOUT);
  int* chunkState = (int*)(ws + CHUNKSTATE_OFF);

  hipLaunchKernelGGL(prep_kernel, dim3(1), dim3(512), 0, stream,
                     pa, edges, W1, b1, W2, b2, W3, b3, ws);
  hipLaunchKernelGGL(mlp_kernel, dim3(T_STEPS / 64), dim3(256), 0, stream,
                     times, ws, lg64);
  hipLaunchKernelGGL(chunk_tables_kernel, dim3(NCHUNK / 4), dim3(256), 0, stream,
                     lg64, ws, chunkG, ftab);
  hipLaunchKernelGGL(super_compose_kernel, dim3(NSUPER / 4), dim3(256), 0, stream,
                     chunkG, superS);
  hipLaunchKernelGGL(super_walk_kernel, dim3(1), dim3(64), 0, stream,
                     superS, supState);
  hipLaunchKernelGGL(chunk_states_kernel, dim3(NSUPER / 4), dim3(256), 0, stream,
                     chunkG, supState, chunkState);
  hipLaunchKernelGGL(finalize_kernel, dim3(NCHUNK / 4), dim3(256), 0, stream,
                     lg64, ws, chunkState, ftab, (float*)d_out);
}

// Round 6
// 151.693 us; speedup vs baseline: 1.9175x; 1.0086x over previous
//
#include <hip/hip_runtime.h>

#define T_STEPS 65536
#define NZ 64
#define NH1 128
#define NH2 64
#define NEDGE 512
#define NCHUNK 8192
#define CL 8            // timesteps per chunk (T_STEPS / NCHUNK)
#define NSUPER 128
#define SUP_L 64        // chunks per super (NCHUNK / NSUPER)

// ---- ws layout (bytes). Base need = 33,694,720 (== round-3 proven size)
#define ADJ_OFF        0          // 64 * u64
#define BASE1_OFF      512        // 128 * f64
#define W1T_OFF        1536       // 128 * f64
#define NBRT_OFF       2560       // 64*64 u8, transposed [k][z]
#define MAXDEG_OFF     6656       // i32
#define CHUNKSTATE_OFF 6720       // NCHUNK * i32 = 32768 (ends 39488)
#define W2D_OFF        40960      // 128*64 f64 = 65536  ([h][j])
#define W3D_OFF        106496     // 64*64 f64 = 32768   ([j][z])
#define B2D_OFF        139264     // 64 f64
#define B3D_OFF        139776     // 64 f64
#define LG64_OFF       140288     // 64*T f64 (z-major: lg64[z*T + t]) = 32MB
#define FTAB_OFF       (LG64_OFF + (size_t)T_STEPS * NZ * 8)   // T*64 u8 = 4MB (optional)
#define WS_NEED_FTAB   (FTAB_OFF + (size_t)T_STEPS * NZ)

// ---- d_out used as scratch before finalize overwrites it (deterministic)
#define CHUNKG_DOUT    0          // NCHUNK*64 u8 = 524288
#define SUPERS_DOUT    524288     // NSUPER*64 u8 = 8192
#define SUPSTATE_DOUT  532480     // NSUPER * i32 = 512

typedef unsigned long long ull;

// ---------------------------------------------------------------------------
// K1: adjacency bitmasks, padded neighbor lists, f64 weight precompute.
// ---------------------------------------------------------------------------
__global__ void prep_kernel(const float* __restrict__ pa,
                            const int* __restrict__ edges,
                            const float* __restrict__ W1,
                            const float* __restrict__ b1,
                            const float* __restrict__ W2,
                            const float* __restrict__ b2,
                            const float* __restrict__ W3,
                            const float* __restrict__ b3,
                            unsigned char* ws) {
  ull* adj = (ull*)(ws + ADJ_OFF);
  double* base1 = (double*)(ws + BASE1_OFF);
  double* w1t   = (double*)(ws + W1T_OFF);
  unsigned char* nbrT = ws + NBRT_OFF;
  double* W2d = (double*)(ws + W2D_OFF);
  double* W3d = (double*)(ws + W3D_OFF);
  double* b2d = (double*)(ws + B2D_OFF);
  double* b3d = (double*)(ws + B3D_OFF);
  __shared__ int smax;
  __shared__ int sdeg[NZ];
  int tid = threadIdx.x;
  if (tid == 0) smax = 0;
  if (tid < NZ) adj[tid] = 0ull;
  __syncthreads();
  if (tid < NEDGE) {
    int e0 = edges[tid];
    int e1 = edges[NEDGE + tid];
    atomicOr(&adj[e0], 1ull << e1);
    atomicOr(&adj[e1], 1ull << e0);
  }
  if (tid < NZ) atomicOr(&adj[tid], 1ull << tid);  // self loops
  if (tid < NH1) {
    double acc = (double)b1[tid];
    for (int d = 0; d < 64; ++d)
      acc += (double)pa[d] * (double)W1[d * NH1 + tid];
    base1[tid] = acc;
    w1t[tid] = (double)W1[64 * NH1 + tid];
  }
  for (int i = tid; i < NH1 * NH2; i += 512) W2d[i] = (double)W2[i];
  for (int i = tid; i < NH2 * NZ; i += 512)  W3d[i] = (double)W3[i];
  if (tid < NH2) b2d[tid] = (double)b2[tid];
  if (tid < NZ)  b3d[tid] = (double)b3[tid];
  __syncthreads();
  if (tid < NZ) {
    ull m = adj[tid];
    int deg = 0;
    while (m) {
      int j = __builtin_ctzll(m);
      m &= m - 1;
      nbrT[deg * 64 + tid] = (unsigned char)j;
      ++deg;
    }
    sdeg[tid] = deg;
    atomicMax(&smax, deg);
  }
  __syncthreads();
  if (tid < NZ) {
    int deg = sdeg[tid];
    unsigned char j0 = nbrT[0 * 64 + tid];  // deg >= 1 (self loop)
    for (int k = deg; k < smax; ++k) nbrT[k * 64 + tid] = j0;
  }
  if (tid == 0) *(int*)(ws + MAXDEG_OFF) = smax;
}

// ---------------------------------------------------------------------------
// K2 (fused): MLP + per-chunk transition tables.
// 512 threads = 8 waves over the SAME 64 timesteps (lane = t).
// Phase A: wave w computes h2[j], j in [8w,8w+8) (acc[8]; weights via
//   wave-uniform SGPR streams), exchange through padded [64][65] LDS tile.
// Phase B: layer 3 -> logits z in [8w,8w+8); store z-major to lg64 AND
//   park logits in the same tile as [z][t].
// Phase C: wave w builds chunk c = blockIdx*8+w: per-step argmax via
//   butterfly + best-neighbor scan (exact f64, first-index ties), emits
//   ftab rows and the composed chunkG table. chunk_tables_kernel deleted.
// ---------------------------------------------------------------------------
__global__ __launch_bounds__(512) void mlp_tables_kernel(
    const float* __restrict__ times,
    const unsigned char* __restrict__ ws_ro,
    double* __restrict__ lg64,
    unsigned char* __restrict__ chunkG,
    unsigned char* __restrict__ ftab) {
  __shared__ double tile[64][65];       // 33.3KB, padded (2-4 way banks)
  __shared__ unsigned char nbrTs[4096];
  const double* __restrict__ base1 = (const double*)(ws_ro + BASE1_OFF);
  const double* __restrict__ w1t   = (const double*)(ws_ro + W1T_OFF);
  const double* __restrict__ W2d   = (const double*)(ws_ro + W2D_OFF);
  const double* __restrict__ W3d   = (const double*)(ws_ro + W3D_OFF);
  const double* __restrict__ b2d   = (const double*)(ws_ro + B2D_OFF);
  const double* __restrict__ b3d   = (const double*)(ws_ro + B3D_OFF);

  int tid = threadIdx.x, lane = tid & 63, wv = tid >> 6;
  // wave-uniform j-slice base, forced into SGPR so weight loads scalarize
  int j0 = __builtin_amdgcn_readfirstlane(wv << 3);
  int t0 = blockIdx.x * 64;
  double tv = (double)times[t0 + lane];

  for (int i = tid; i < 1024; i += 512)
    ((unsigned int*)nbrTs)[i] = ((const unsigned int*)(ws_ro + NBRT_OFF))[i];

  // ---- Phase A: layers 1+2
  double acc[8];
  #pragma unroll
  for (int jj = 0; jj < 8; ++jj) acc[jj] = b2d[j0 + jj];
  #pragma unroll 2
  for (int h = 0; h < NH1; ++h) {
    double a = fma(tv, w1t[h], base1[h]);
    a = a > 0.0 ? a : 0.0;
    const double* __restrict__ row = W2d + h * 64 + j0;
    #pragma unroll
    for (int jj = 0; jj < 8; ++jj) acc[jj] = fma(a, row[jj], acc[jj]);
  }
  #pragma unroll
  for (int jj = 0; jj < 8; ++jj)
    tile[j0 + jj][lane] = acc[jj] > 0.0 ? acc[jj] : 0.0;
  __syncthreads();

  // ---- Phase B: layer 3
  double lg[8];
  #pragma unroll
  for (int zz = 0; zz < 8; ++zz) lg[zz] = b3d[j0 + zz];
  #pragma unroll 2
  for (int j = 0; j < 64; ++j) {
    double hv = tile[j][lane];
    const double* __restrict__ row = W3d + j * 64 + j0;
    #pragma unroll
    for (int zz = 0; zz < 8; ++zz) lg[zz] = fma(hv, row[zz], lg[zz]);
  }
  __syncthreads();  // all waves done reading h2 from the tile
  #pragma unroll
  for (int zz = 0; zz < 8; ++zz) {
    lg64[(size_t)(j0 + zz) * T_STEPS + t0 + lane] = lg[zz];
    tile[j0 + zz][lane] = lg[zz];  // repark as [z][t]
  }
  __syncthreads();

  // ---- Phase C: tables. wave wv owns chunk c; lane = z.
  const int maxdeg = *(const int*)(ws_ro + MAXDEG_OFF);
  ull mask = ((const ull*)(ws_ro + ADJ_OFF))[lane];
  int c = blockIdx.x * 8 + wv;
  int tl0 = wv * 8;  // this chunk's local t offset in the tile

  double lgv[CL];
  #pragma unroll
  for (int i = 0; i < CL; ++i) lgv[i] = tile[lane][tl0 + i];

  double vn[CL];
  int jn[CL];
  #pragma unroll
  for (int i = 0; i < CL; ++i) { vn[i] = -1.0e300; jn[i] = 0; }
  #pragma unroll 2
  for (int k = 0; k < maxdeg; ++k) {
    int j = nbrTs[k * 64 + lane];
    #pragma unroll
    for (int i = 0; i < CL; ++i) {
      double val = tile[j][tl0 + i];
      if (val > vn[i]) { vn[i] = val; jn[i] = j; }  // ascending j, strict >
    }
  }

  int F[CL];
  #pragma unroll
  for (int i = 0; i < CL; ++i) {
    double v = lgv[i];
    int idx = lane;
    #pragma unroll
    for (int off = 1; off < 64; off <<= 1) {
      double ov = __shfl_xor(v, off, 64);
      int oi = __shfl_xor(idx, off, 64);
      if (ov > v || (ov == v && oi < idx)) { v = ov; idx = oi; }
    }
    int f;
    if ((mask >> idx) & 1ull) f = idx;
    else {
      double vg = v - 1.0;
      if (vn[i] > vg) f = jn[i];
      else if (vn[i] < vg) f = idx;
      else f = jn[i] < idx ? jn[i] : idx;
    }
    F[i] = f;
  }
  if (ftab) {
    #pragma unroll
    for (int i = 0; i < CL; ++i)
      ftab[(size_t)(c * CL + i) * 64 + lane] = (unsigned char)F[i];
  }
  int cur = lane;
  #pragma unroll
  for (int i = 0; i < CL; ++i) cur = __shfl(F[i], cur, 64);
  chunkG[(size_t)c * 64 + lane] = (unsigned char)cur;
}

// ---------------------------------------------------------------------------
// K4: compose SUP_L chunk tables into each super table.
// ---------------------------------------------------------------------------
__global__ void super_compose_kernel(const unsigned char* __restrict__ chunkG,
                                     unsigned char* __restrict__ superS) {
  int lane = threadIdx.x & 63, wv = threadIdx.x >> 6;
  int k = blockIdx.x * 4 + wv;
  int cur = lane;
  #pragma unroll 8
  for (int c = k * SUP_L; c < (k + 1) * SUP_L; ++c) {
    int g = chunkG[(size_t)c * 64 + lane];
    cur = __shfl(g, cur, 64);
  }
  superS[(size_t)k * 64 + lane] = (unsigned char)cur;
}

// ---------------------------------------------------------------------------
// K5: sequential walk over NSUPER super tables (1 wave, LDS-staged).
// ---------------------------------------------------------------------------
__global__ void super_walk_kernel(const unsigned char* __restrict__ superS,
                                  int* __restrict__ supState) {
  __shared__ unsigned char ssup[NSUPER * 64];
  int lane = threadIdx.x;
  for (int i = lane; i < NSUPER * 16; i += 64)
    ((unsigned int*)ssup)[i] = ((const unsigned int*)superS)[i];
  __syncthreads();
  int s = 0;
  if (lane == 0) supState[0] = 0;
  for (int k = 0; k < NSUPER; ++k) {
    int v = ssup[k * 64 + lane];
    s = __shfl(v, s, 64);
    if (lane == 0 && k + 1 < NSUPER) supState[k + 1] = s;
  }
}

// ---------------------------------------------------------------------------
// K6: per-chunk start states — LDS-staged walk.
// ---------------------------------------------------------------------------
__global__ __launch_bounds__(256) void chunk_states_kernel(
    const unsigned char* __restrict__ chunkG,
    const int* __restrict__ supState,
    int* __restrict__ chunkState) {
  __shared__ unsigned char g[4][SUP_L * 64];
  __shared__ int sbuf[4][SUP_L];
  int tid = threadIdx.x, lane = tid & 63, wv = tid >> 6;
  int k = blockIdx.x * 4 + wv;
  const unsigned int* src = (const unsigned int*)(chunkG + (size_t)k * SUP_L * 64);
  unsigned int* dst = (unsigned int*)g[wv];
  #pragma unroll 4
  for (int i = lane; i < SUP_L * 16; i += 64) dst[i] = src[i];
  int s = supState[k];
  for (int c = 0; c < SUP_L; ++c) {
    if (lane == 0) sbuf[wv][c] = s;
    s = g[wv][c * 64 + s];
  }
  chunkState[k * SUP_L + lane] = sbuf[wv][lane];
}

// ---------------------------------------------------------------------------
// K7: finalize. If ftab != null: streaming — LDS-staged F lookups, no
// butterfly. Else: fallback f64 shfl-argmax walk.
// ---------------------------------------------------------------------------
__global__ __launch_bounds__(256) void finalize_kernel(
    const double* __restrict__ lg64, const unsigned char* __restrict__ ws_ro,
    const int* __restrict__ chunkState, const unsigned char* __restrict__ ftab,
    float* __restrict__ out) {
  __shared__ ull adjs[64];
  __shared__ unsigned char fstage[4][CL * 64];
  int tid = threadIdx.x, lane = tid & 63, wv = tid >> 6;
  if (tid < 64) adjs[tid] = ((const ull*)(ws_ro + ADJ_OFF))[tid];
  __syncthreads();
  int c = blockIdx.x * 4 + wv;
  int s = chunkState[c];
  size_t tb = (size_t)c * CL * 64;

  double lgv[CL];
  #pragma unroll
  for (int i = 0; i < CL; ++i)
    lgv[i] = lg64[(size_t)lane * T_STEPS + c * CL + i];  // 64B contig per lane

  if (ftab) {
    unsigned int* dst = (unsigned int*)fstage[wv];
    const unsigned int* src = (const unsigned int*)(ftab + tb);
    #pragma unroll
    for (int i = lane; i < CL * 16; i += 64) dst[i] = src[i];
    // wave-private LDS; compiler inserts the lgkm wait
    #pragma unroll
    for (int i = 0; i < CL; ++i) {
      int bit = (int)((adjs[s] >> lane) & 1ull);
      out[tb + i * 64 + lane] = (float)(bit ? lgv[i] : lgv[i] - 1.0);
      s = fstage[wv][i * 64 + s];  // uniform broadcast read
    }
  } else {
    #pragma unroll
    for (int i = 0; i < CL; ++i) {
      int bit = (int)((adjs[s] >> lane) & 1ull);
      double v = bit ? lgv[i] : lgv[i] - 1.0;
      out[tb + i * 64 + lane] = (float)v;
      int idx = lane;
      #pragma unroll
      for (int off = 1; off < 64; off <<= 1) {
        double ov = __shfl_xor(v, off, 64);
        int oi = __shfl_xor(idx, off, 64);
        if (ov > v || (ov == v && oi < idx)) { v = ov; idx = oi; }
      }
      s = idx;
    }
  }
}

// ---------------------------------------------------------------------------
extern "C" void kernel_launch(void* const* d_in, const int* in_sizes, int n_in,
                              void* d_out, int out_size, void* d_ws, size_t ws_size,
                              hipStream_t stream) {
  const float* pa    = (const float*)d_in[0];
  const float* times = (const float*)d_in[1];
  // d_in[2] zone_features: unused by the reference
  const int*   edges = (const int*)d_in[3];
  const float* W1    = (const float*)d_in[4];
  const float* b1    = (const float*)d_in[5];
  const float* W2    = (const float*)d_in[6];
  const float* b2    = (const float*)d_in[7];
  const float* W3    = (const float*)d_in[8];
  const float* b3    = (const float*)d_in[9];

  unsigned char* ws = (unsigned char*)d_ws;
  unsigned char* outb = (unsigned char*)d_out;  // scratch until finalize
  double* lg64 = (double*)(ws + LG64_OFF);
  unsigned char* ftab = (ws_size >= WS_NEED_FTAB) ? (ws + FTAB_OFF) : nullptr;
  unsigned char* chunkG = outb + CHUNKG_DOUT;
  unsigned char* superS = outb + SUPERS_DOUT;
  int* supState = (int*)(outb + SUPSTATE_DOUT);
  int* chunkState = (int*)(ws + CHUNKSTATE_OFF);

  hipLaunchKernelGGL(prep_kernel, dim3(1), dim3(512), 0, stream,
                     pa, edges, W1, b1, W2, b2, W3, b3, ws);
  hipLaunchKernelGGL(mlp_tables_kernel, dim3(T_STEPS / 64), dim3(512), 0, stream,
                     times, ws, lg64, chunkG, ftab);
  hipLaunchKernelGGL(super_compose_kernel, dim3(NSUPER / 4), dim3(256), 0, stream,
                     chunkG, superS);
  hipLaunchKernelGGL(super_walk_kernel, dim3(1), dim3(64), 0, stream,
                     superS, supState);
  hipLaunchKernelGGL(chunk_states_kernel, dim3(NSUPER / 4), dim3(256), 0, stream,
                     chunkG, supState, chunkState);
  hipLaunchKernelGGL(finalize_kernel, dim3(NCHUNK / 4), dim3(256), 0, stream,
                     lg64, ws, chunkState, ftab, (float*)d_out);
}

// Round 7
// 130.887 us; speedup vs baseline: 2.2223x; 1.1590x over previous
//
#include <hip/hip_runtime.h>

#define T_STEPS 65536
#define NZ 64
#define NH1 128
#define NH2 64
#define NEDGE 512
#define NCHUNK 8192
#define CL 8            // timesteps per chunk (T_STEPS / NCHUNK)
#define NSUPER 128
#define SUP_L 64        // chunks per super (NCHUNK / NSUPER)

// ---- ws layout (bytes). Base need = 33,694,720 (== round-3 proven size)
#define ADJ_OFF        0          // 64 * u64
#define BASE1_OFF      512        // 128 * f64
#define W1T_OFF        1536      // 128 * f64
#define NBRP_OFF       2560      // 64 z * 16 u32 words (4 packed u8 ids each) = 4096
#define DEGS_OFF       6656      // 64 u8: per-z u32-word count (ceil(deg/4))
#define CHUNKSTATE_OFF 6720      // NCHUNK * i32 = 32768 (ends 39488)
#define W2D_OFF        40960     // 128*64 f64 = 65536  ([h][j])
#define W3D_OFF        106496    // 64*64 f64 = 32768   ([j][z])
#define B2D_OFF        139264    // 64 f64
#define B3D_OFF        139776    // 64 f64
#define LG64_OFF       140288    // 64*T f64 (z-major: lg64[z*T + t]) = 32MB
#define FTAB_OFF       (LG64_OFF + (size_t)T_STEPS * NZ * 8)   // T*64 u8 = 4MB (optional)
#define WS_NEED_FTAB   (FTAB_OFF + (size_t)T_STEPS * NZ)

// ---- d_out used as scratch before finalize overwrites it (deterministic)
#define CHUNKG_DOUT    0          // NCHUNK*64 u8 = 524288
#define SUPERS_DOUT    524288     // NSUPER*64 u8 = 8192
#define SUPSTATE_DOUT  532480     // NSUPER * i32 = 512

typedef unsigned long long ull;
typedef unsigned int u32;
typedef unsigned char u8;

// ---------------------------------------------------------------------------
// K1: adjacency bitmasks, u32-packed per-z neighbor lists (ascending,
// padded with first-neighbor to word boundary), f64 weight precompute.
// ---------------------------------------------------------------------------
__global__ void prep_kernel(const float* __restrict__ pa,
                            const int* __restrict__ edges,
                            const float* __restrict__ W1,
                            const float* __restrict__ b1,
                            const float* __restrict__ W2,
                            const float* __restrict__ b2,
                            const float* __restrict__ W3,
                            const float* __restrict__ b3,
                            unsigned char* ws) {
  ull* adj = (ull*)(ws + ADJ_OFF);
  double* base1 = (double*)(ws + BASE1_OFF);
  double* w1t   = (double*)(ws + W1T_OFF);
  double* W2d = (double*)(ws + W2D_OFF);
  double* W3d = (double*)(ws + W3D_OFF);
  double* b2d = (double*)(ws + B2D_OFF);
  double* b3d = (double*)(ws + B3D_OFF);
  int tid = threadIdx.x;
  if (tid < NZ) adj[tid] = 0ull;
  __syncthreads();
  if (tid < NEDGE) {
    int e0 = edges[tid];
    int e1 = edges[NEDGE + tid];
    atomicOr(&adj[e0], 1ull << e1);
    atomicOr(&adj[e1], 1ull << e0);
  }
  if (tid < NZ) atomicOr(&adj[tid], 1ull << tid);  // self loops
  if (tid < NH1) {
    double acc = (double)b1[tid];
    for (int d = 0; d < 64; ++d)
      acc += (double)pa[d] * (double)W1[d * NH1 + tid];
    base1[tid] = acc;
    w1t[tid] = (double)W1[64 * NH1 + tid];
  }
  for (int i = tid; i < NH1 * NH2; i += 512) W2d[i] = (double)W2[i];
  for (int i = tid; i < NH2 * NZ; i += 512)  W3d[i] = (double)W3[i];
  if (tid < NH2) b2d[tid] = (double)b2[tid];
  if (tid < NZ)  b3d[tid] = (double)b3[tid];
  __syncthreads();
  if (tid < NZ) {
    ull m = adj[tid];
    u32 wbuf[16];
    #pragma unroll
    for (int i = 0; i < 16; ++i) wbuf[i] = 0u;
    int deg = 0, jfirst = 0;
    while (m) {
      int j = __builtin_ctzll(m);
      m &= m - 1;
      if (deg == 0) jfirst = j;
      wbuf[deg >> 2] |= (u32)j << ((deg & 3) * 8);
      ++deg;
    }
    int padded = (deg + 3) & ~3;
    for (int k = deg; k < padded; ++k)
      wbuf[k >> 2] |= (u32)jfirst << ((k & 3) * 8);
    u32* np = (u32*)(ws + NBRP_OFF) + tid * 16;
    #pragma unroll
    for (int i = 0; i < 16; ++i) np[i] = wbuf[i];
    (ws + DEGS_OFF)[tid] = (u8)(padded >> 2);
  }
}

// ---------------------------------------------------------------------------
// K2 (fused): MLP + per-chunk transition tables, lane=t throughout.
// 512 threads = 8 waves over the SAME 64 timesteps (lane = t).
// A: wave w computes h2[j], j in [8w,8w+8) via SGPR weight streams.
// B: layer 3 -> logits z in [8w,8w+8); store z-major; park in tile as [z][t].
// C1: per-wave redundant global max over z (row reads, no shuffles).
// C2: wave w builds F[t][z] for its z-slice: uniform-row neighbor scan
//     (packed scalar neighbor lists), exact f64, first-index ties.
// C3: coalesced ftab write; C4: compose chunkG via 8 u8 gathers.
// ---------------------------------------------------------------------------
__global__ __launch_bounds__(512) void mlp_tables_kernel(
    const float* __restrict__ times,
    const unsigned char* __restrict__ ws_ro,
    double* __restrict__ lg64,
    unsigned char* __restrict__ chunkG,
    unsigned char* __restrict__ ftab) {
  __shared__ double tile[64][64];   // 32KB, [row][t]; rows only -> no pad
  __shared__ u8 F_lds[64][68];      // 4.25KB, [t][z] stride 68 (17 words)
  const double* __restrict__ base1 = (const double*)(ws_ro + BASE1_OFF);
  const double* __restrict__ w1t   = (const double*)(ws_ro + W1T_OFF);
  const double* __restrict__ W2d   = (const double*)(ws_ro + W2D_OFF);
  const double* __restrict__ W3d   = (const double*)(ws_ro + W3D_OFF);
  const double* __restrict__ b2d   = (const double*)(ws_ro + B2D_OFF);
  const double* __restrict__ b3d   = (const double*)(ws_ro + B3D_OFF);
  const u32* __restrict__ nbrP = (const u32*)(ws_ro + NBRP_OFF);
  const u8*  __restrict__ degs = ws_ro + DEGS_OFF;
  const ull* __restrict__ adjg = (const ull*)(ws_ro + ADJ_OFF);

  int tid = threadIdx.x, lane = tid & 63, wv = tid >> 6;
  int jbase = __builtin_amdgcn_readfirstlane(wv << 3);  // SGPR j-slice base
  int t0 = blockIdx.x * 64;
  double tv = (double)times[t0 + lane];

  // ---- Phase A: layers 1+2
  double acc[8];
  #pragma unroll
  for (int jj = 0; jj < 8; ++jj) acc[jj] = b2d[jbase + jj];
  #pragma unroll 2
  for (int h = 0; h < NH1; ++h) {
    double a = fma(tv, w1t[h], base1[h]);
    a = a > 0.0 ? a : 0.0;
    const double* __restrict__ row = W2d + h * 64 + jbase;
    #pragma unroll
    for (int jj = 0; jj < 8; ++jj) acc[jj] = fma(a, row[jj], acc[jj]);
  }
  #pragma unroll
  for (int jj = 0; jj < 8; ++jj)
    tile[jbase + jj][lane] = acc[jj] > 0.0 ? acc[jj] : 0.0;
  __syncthreads();

  // ---- Phase B: layer 3
  double lg[8];
  #pragma unroll
  for (int zz = 0; zz < 8; ++zz) lg[zz] = b3d[jbase + zz];
  #pragma unroll 2
  for (int j = 0; j < 64; ++j) {
    double hv = tile[j][lane];
    const double* __restrict__ row = W3d + j * 64 + jbase;
    #pragma unroll
    for (int zz = 0; zz < 8; ++zz) lg[zz] = fma(hv, row[zz], lg[zz]);
  }
  __syncthreads();  // all waves done reading h2
  #pragma unroll
  for (int zz = 0; zz < 8; ++zz) {
    lg64[(size_t)(jbase + zz) * T_STEPS + t0 + lane] = lg[zz];
    tile[jbase + zz][lane] = lg[zz];  // repark logits as [z][t]
  }
  __syncthreads();

  // ---- Phase C1: global argmax over z per t (lane = t), first-index ties
  double vmax = tile[0][lane];
  int jmax = 0;
  #pragma unroll 4
  for (int z = 1; z < 64; ++z) {
    double v = tile[z][lane];
    if (v > vmax) { vmax = v; jmax = z; }
  }
  double vgap = vmax - 1.0;

  // ---- Phase C2: F[t][z] for z in this wave's slice
  #pragma unroll
  for (int zz = 0; zz < 8; ++zz) {
    int z = __builtin_amdgcn_readfirstlane(jbase + zz);
    ull az = adjg[z];                                    // uniform s_load
    int nk4 = __builtin_amdgcn_readfirstlane((int)degs[z]);
    double vn = -1.0e300;
    int jn = 0;
    for (int k4 = 0; k4 < nk4; ++k4) {
      u32 w4 = nbrP[z * 16 + k4];                        // uniform s_load
      #pragma unroll
      for (int b = 0; b < 4; ++b) {
        int j = (w4 >> (b * 8)) & 63;                    // uniform
        double val = tile[j][lane];                      // uniform row read
        if (val > vn) { vn = val; jn = j; }              // ascending, strict >
      }
    }
    int bit = (int)((az >> jmax) & 1ull);
    int fnb = (vn > vgap) ? jn : ((vn < vgap) ? jmax : (jn < jmax ? jn : jmax));
    F_lds[lane][z] = (u8)(bit ? jmax : fnb);
  }
  __syncthreads();

  // ---- Phase C3: coalesced ftab write (u32 packed straight from F_lds)
  if (ftab) {
    u32* fo = (u32*)(ftab + (size_t)t0 * 64);
    #pragma unroll
    for (int r = 0; r < 2; ++r) {
      int i = tid + r * 512;          // 0..1023 words = 64t x 16 words
      int t = i >> 4, z4 = (i & 15) << 2;
      fo[i] = *(const u32*)&F_lds[t][z4];
    }
  }

  // ---- Phase C4: compose this wave's chunk table (lane = z)
  int c = blockIdx.x * 8 + wv;
  int cur = lane;
  #pragma unroll
  for (int i = 0; i < CL; ++i) cur = F_lds[wv * 8 + i][cur];
  chunkG[(size_t)c * 64 + lane] = (u8)cur;
}

// ---------------------------------------------------------------------------
// K4: compose SUP_L chunk tables into each super table.
// ---------------------------------------------------------------------------
__global__ void super_compose_kernel(const unsigned char* __restrict__ chunkG,
                                     unsigned char* __restrict__ superS) {
  int lane = threadIdx.x & 63, wv = threadIdx.x >> 6;
  int k = blockIdx.x * 4 + wv;
  int cur = lane;
  #pragma unroll 8
  for (int c = k * SUP_L; c < (k + 1) * SUP_L; ++c) {
    int g = chunkG[(size_t)c * 64 + lane];
    cur = __shfl(g, cur, 64);
  }
  superS[(size_t)k * 64 + lane] = (unsigned char)cur;
}

// ---------------------------------------------------------------------------
// K5: sequential walk over NSUPER super tables (1 wave, LDS-staged).
// ---------------------------------------------------------------------------
__global__ void super_walk_kernel(const unsigned char* __restrict__ superS,
                                  int* __restrict__ supState) {
  __shared__ unsigned char ssup[NSUPER * 64];
  int lane = threadIdx.x;
  for (int i = lane; i < NSUPER * 16; i += 64)
    ((unsigned int*)ssup)[i] = ((const unsigned int*)superS)[i];
  __syncthreads();
  int s = 0;
  if (lane == 0) supState[0] = 0;
  for (int k = 0; k < NSUPER; ++k) {
    int v = ssup[k * 64 + lane];
    s = __shfl(v, s, 64);
    if (lane == 0 && k + 1 < NSUPER) supState[k + 1] = s;
  }
}

// ---------------------------------------------------------------------------
// K6: per-chunk start states — LDS-staged walk.
// ---------------------------------------------------------------------------
__global__ __launch_bounds__(256) void chunk_states_kernel(
    const unsigned char* __restrict__ chunkG,
    const int* __restrict__ supState,
    int* __restrict__ chunkState) {
  __shared__ unsigned char g[4][SUP_L * 64];
  __shared__ int sbuf[4][SUP_L];
  int tid = threadIdx.x, lane = tid & 63, wv = tid >> 6;
  int k = blockIdx.x * 4 + wv;
  const unsigned int* src = (const unsigned int*)(chunkG + (size_t)k * SUP_L * 64);
  unsigned int* dst = (unsigned int*)g[wv];
  #pragma unroll 4
  for (int i = lane; i < SUP_L * 16; i += 64) dst[i] = src[i];
  int s = supState[k];
  for (int c = 0; c < SUP_L; ++c) {
    if (lane == 0) sbuf[wv][c] = s;
    s = g[wv][c * 64 + s];
  }
  chunkState[k * SUP_L + lane] = sbuf[wv][lane];
}

// ---------------------------------------------------------------------------
// K7: finalize. If ftab != null: streaming — LDS-staged F lookups, no
// butterfly. Else: fallback f64 shfl-argmax walk.
// ---------------------------------------------------------------------------
__global__ __launch_bounds__(256) void finalize_kernel(
    const double* __restrict__ lg64, const unsigned char* __restrict__ ws_ro,
    const int* __restrict__ chunkState, const unsigned char* __restrict__ ftab,
    float* __restrict__ out) {
  __shared__ ull adjs[64];
  __shared__ unsigned char fstage[4][CL * 64];
  int tid = threadIdx.x, lane = tid & 63, wv = tid >> 6;
  if (tid < 64) adjs[tid] = ((const ull*)(ws_ro + ADJ_OFF))[tid];
  __syncthreads();
  int c = blockIdx.x * 4 + wv;
  int s = chunkState[c];
  size_t tb = (size_t)c * CL * 64;

  double lgv[CL];
  #pragma unroll
  for (int i = 0; i < CL; ++i)
    lgv[i] = lg64[(size_t)lane * T_STEPS + c * CL + i];  // 64B contig per lane

  if (ftab) {
    unsigned int* dst = (unsigned int*)fstage[wv];
    const unsigned int* src = (const unsigned int*)(ftab + tb);
    #pragma unroll
    for (int i = lane; i < CL * 16; i += 64) dst[i] = src[i];
    // wave-private LDS; compiler inserts the lgkm wait
    #pragma unroll
    for (int i = 0; i < CL; ++i) {
      int bit = (int)((adjs[s] >> lane) & 1ull);
      out[tb + i * 64 + lane] = (float)(bit ? lgv[i] : lgv[i] - 1.0);
      s = fstage[wv][i * 64 + s];  // uniform broadcast read
    }
  } else {
    #pragma unroll
    for (int i = 0; i < CL; ++i) {
      int bit = (int)((adjs[s] >> lane) & 1ull);
      double v = bit ? lgv[i] : lgv[i] - 1.0;
      out[tb + i * 64 + lane] = (float)v;
      int idx = lane;
      #pragma unroll
      for (int off = 1; off < 64; off <<= 1) {
        double ov = __shfl_xor(v, off, 64);
        int oi = __shfl_xor(idx, off, 64);
        if (ov > v || (ov == v && oi < idx)) { v = ov; idx = oi; }
      }
      s = idx;
    }
  }
}

// ---------------------------------------------------------------------------
extern "C" void kernel_launch(void* const* d_in, const int* in_sizes, int n_in,
                              void* d_out, int out_size, void* d_ws, size_t ws_size,
                              hipStream_t stream) {
  const float* pa    = (const float*)d_in[0];
  const float* times = (const float*)d_in[1];
  // d_in[2] zone_features: unused by the reference
  const int*   edges = (const int*)d_in[3];
  const float* W1    = (const float*)d_in[4];
  const float* b1    = (const float*)d_in[5];
  const float* W2    = (const float*)d_in[6];
  const float* b2    = (const float*)d_in[7];
  const float* W3    = (const float*)d_in[8];
  const float* b3    = (const float*)d_in[9];

  unsigned char* ws = (unsigned char*)d_ws;
  unsigned char* outb = (unsigned char*)d_out;  // scratch until finalize
  double* lg64 = (double*)(ws + LG64_OFF);
  unsigned char* ftab = (ws_size >= WS_NEED_FTAB) ? (ws + FTAB_OFF) : nullptr;
  unsigned char* chunkG = outb + CHUNKG_DOUT;
  unsigned char* superS = outb + SUPERS_DOUT;
  int* supState = (int*)(outb + SUPSTATE_DOUT);
  int* chunkState = (int*)(ws + CHUNKSTATE_OFF);

  hipLaunchKernelGGL(prep_kernel, dim3(1), dim3(512), 0, stream,
                     pa, edges, W1, b1, W2, b2, W3, b3, ws);
  hipLaunchKernelGGL(mlp_tables_kernel, dim3(T_STEPS / 64), dim3(512), 0, stream,
                     times, ws, lg64, chunkG, ftab);
  hipLaunchKernelGGL(super_compose_kernel, dim3(NSUPER / 4), dim3(256), 0, stream,
                     chunkG, superS);
  hipLaunchKernelGGL(super_walk_kernel, dim3(1), dim3(64), 0, stream,
                     superS, supState);
  hipLaunchKernelGGL(chunk_states_kernel, dim3(NSUPER / 4), dim3(256), 0, stream,
                     chunkG, supState, chunkState);
  hipLaunchKernelGGL(finalize_kernel, dim3(NCHUNK / 4), dim3(256), 0, stream,
                     lg64, ws, chunkState, ftab, (float*)d_out);
}

// Round 8
// 108.296 us; speedup vs baseline: 2.6860x; 1.2086x over previous
//
#include <hip/hip_runtime.h>

#define T_STEPS 65536
#define NZ 64
#define NH1 128
#define NH2 64
#define NEDGE 512
#define NCHUNK 8192
#define CL 8            // timesteps per chunk (T_STEPS / NCHUNK)
#define NSUPER 128
#define SUP_L 64        // chunks per super (NCHUNK / NSUPER)

// ---- ws layout (bytes). Total need = 140288 + 16MB + 4MB ~= 21.1MB
// (proven available: round-2+ kernels required 33.7MB and passed)
#define ADJ_OFF        0          // 64 * u64
#define BASE1_OFF      512        // 128 * f64
#define W1T_OFF        1536      // 128 * f64
#define NBRP_OFF       2560      // 64 z * 16 u32 words (4 packed u8 ids each) = 4096
#define DEGS_OFF       6656      // 64 u8: per-z u32-word count (ceil(deg/4))
#define CHUNKSTATE_OFF 6720      // NCHUNK * i32 = 32768 (ends 39488)
#define B2D_OFF        139264    // 64 f64
#define B3D_OFF        139776    // 64 f64
#define LG32_OFF       140288    // 64*T f32 (z-major: lg32[z*T + t]) = 16MB
#define FTAB_OFF       (LG32_OFF + (size_t)T_STEPS * NZ * 4)   // T*64 u8 = 4MB

// ---- d_out used as scratch before finalize overwrites it (deterministic)
#define CHUNKG_DOUT    0          // NCHUNK*64 u8 = 524288
#define SUPERS_DOUT    524288     // NSUPER*64 u8 = 8192
#define SUPSTATE_DOUT  532480     // NSUPER * i32 = 512

typedef unsigned long long ull;
typedef unsigned int u32;
typedef unsigned char u8;
typedef double f64x4 __attribute__((ext_vector_type(4)));

// ---------------------------------------------------------------------------
// K1: adjacency bitmasks, u32-packed per-z neighbor lists (ascending,
// padded with first-neighbor to word boundary), f64 bias/base precompute.
// ---------------------------------------------------------------------------
__global__ void prep_kernel(const float* __restrict__ pa,
                            const int* __restrict__ edges,
                            const float* __restrict__ W1,
                            const float* __restrict__ b1,
                            const float* __restrict__ b2,
                            const float* __restrict__ b3,
                            unsigned char* ws) {
  ull* adj = (ull*)(ws + ADJ_OFF);
  double* base1 = (double*)(ws + BASE1_OFF);
  double* w1t   = (double*)(ws + W1T_OFF);
  double* b2d = (double*)(ws + B2D_OFF);
  double* b3d = (double*)(ws + B3D_OFF);
  int tid = threadIdx.x;
  if (tid < NZ) adj[tid] = 0ull;
  __syncthreads();
  if (tid < NEDGE) {
    int e0 = edges[tid];
    int e1 = edges[NEDGE + tid];
    atomicOr(&adj[e0], 1ull << e1);
    atomicOr(&adj[e1], 1ull << e0);
  }
  if (tid < NZ) atomicOr(&adj[tid], 1ull << tid);  // self loops
  if (tid < NH1) {
    double acc = (double)b1[tid];
    for (int d = 0; d < 64; ++d)
      acc += (double)pa[d] * (double)W1[d * NH1 + tid];
    base1[tid] = acc;
    w1t[tid] = (double)W1[64 * NH1 + tid];
  }
  if (tid < NH2) b2d[tid] = (double)b2[tid];
  if (tid < NZ)  b3d[tid] = (double)b3[tid];
  __syncthreads();
  if (tid < NZ) {
    ull m = adj[tid];
    u32 wbuf[16];
    #pragma unroll
    for (int i = 0; i < 16; ++i) wbuf[i] = 0u;
    int deg = 0, jfirst = 0;
    while (m) {
      int j = __builtin_ctzll(m);
      m &= m - 1;
      if (deg == 0) jfirst = j;
      wbuf[deg >> 2] |= (u32)j << ((deg & 3) * 8);
      ++deg;
    }
    int padded = (deg + 3) & ~3;
    for (int k = deg; k < padded; ++k)
      wbuf[k >> 2] |= (u32)jfirst << ((k & 3) * 8);
    u32* np = (u32*)(ws + NBRP_OFF) + tid * 16;
    #pragma unroll
    for (int i = 0; i < 16; ++i) np[i] = wbuf[i];
    (ws + DEGS_OFF)[tid] = (u8)(padded >> 2);
  }
}

// ---------------------------------------------------------------------------
// K2 (fused): MFMA-f64 MLP + per-chunk transition tables.
// 512 threads = 8 waves; block owns 64 timesteps.
// GEMM view: layer2 = [64t x 128h]x[128h x 64j], layer3 = [64t x 64j]x[64j x 64z]
// via v_mfma_f64_16x16x4: wave = 1 M-tile (mt=wv&3) x 2 N-tiles (nt0=(wv>>2)*2).
// A-frag lane layout: A[lane&15][lane>>4]; B[lane>>4][lane&15];
// C/D: col=lane&15, row=(lane>>4)*4+reg.
// W2/W3 staged f32 in LDS (inputs are f32; cvt to f64 exact). h2 exchanged
// as f64 [64][66] tile (padded). Logits parked as lgT[z][66] f64 for phase C;
// f32 copy streamed to lg32 (z-major) for finalize.
// Phase C: C1 split-argmax (8 rows/wave + LDS partial merge, first-index
// ties), C2 uniform-row neighbor scan (packed scalar lists), all f64-exact.
// ---------------------------------------------------------------------------
__global__ __launch_bounds__(512) void mlp_tables_kernel(
    const float* __restrict__ times,
    const float* __restrict__ W2,
    const float* __restrict__ W3,
    const unsigned char* __restrict__ ws_ro,
    float* __restrict__ lg32,
    unsigned char* __restrict__ chunkG,
    unsigned char* __restrict__ ftab) {
  __shared__ double region1[4224];   // 33792B: w2s f32[128][66] -> h2/lgT f64[64][66]
  __shared__ double region2[2112];   // 16896B: w3s f32[64][66] -> {F_lds, pv, pi}
  __shared__ double base1s[NH1], w1ts[NH1];
  __shared__ double b2s[NH2], b3s[NZ];

  float* w2s = (float*)region1;             // [128][66] f32
  float* w3s = (float*)region2;             // [64][66] f32
  double* h2t = region1;                    // [64 t][66] f64
  double* lgT = region1;                    // [64 z][66] f64
  u8* F_lds = (u8*)region2;                 // [64 t][68] u8 = 4352B
  double* pv = (double*)((u8*)region2 + 4352);  // [8][64] f64 = 4096B
  u8* pi = (u8*)region2 + 8448;             // [8][64] u8 = 512B

  int tid = threadIdx.x, lane = tid & 63, wv = tid >> 6;
  int i15 = lane & 15, g = lane >> 4;
  int mt = wv & 3, nt0 = (wv >> 2) * 2;
  int t0 = blockIdx.x * 64;

  // ---- stage weights (f32) + f64 constants
  for (int i = tid; i < NH1 * 64; i += 512) w2s[(i >> 6) * 66 + (i & 63)] = W2[i];
  for (int i = tid; i < NH2 * 64; i += 512) w3s[(i >> 6) * 66 + (i & 63)] = W3[i];
  if (tid < NH1) {
    base1s[tid] = ((const double*)(ws_ro + BASE1_OFF))[tid];
    w1ts[tid]   = ((const double*)(ws_ro + W1T_OFF))[tid];
  } else if (tid < NH1 + NH2) {
    int j = tid - NH1;
    b2s[j] = ((const double*)(ws_ro + B2D_OFF))[j];
  } else if (tid < NH1 + NH2 + NZ) {
    int z = tid - NH1 - NH2;
    b3s[z] = ((const double*)(ws_ro + B3D_OFF))[z];
  }
  double tv = (double)times[t0 + mt * 16 + i15];
  __syncthreads();

  // ---- layer 2 (K=128, 32 MFMA k-steps x 2 N-tiles)
  f64x4 c0, c1;
  {
    double v0 = b2s[nt0 * 16 + i15], v1 = b2s[nt0 * 16 + 16 + i15];
    c0[0] = v0; c0[1] = v0; c0[2] = v0; c0[3] = v0;
    c1[0] = v1; c1[1] = v1; c1[2] = v1; c1[3] = v1;
  }
  #pragma unroll 8
  for (int ks = 0; ks < 32; ++ks) {
    int h = ks * 4 + g;
    double a = fma(tv, w1ts[h], base1s[h]);
    a = a > 0.0 ? a : 0.0;                      // h1 = relu(...), exact f64
    double b0 = (double)w2s[h * 66 + nt0 * 16 + i15];
    double b1 = (double)w2s[h * 66 + nt0 * 16 + 16 + i15];
    c0 = __builtin_amdgcn_mfma_f64_16x16x4f64(a, b0, c0, 0, 0, 0);
    c1 = __builtin_amdgcn_mfma_f64_16x16x4f64(a, b1, c1, 0, 0, 0);
  }
  __syncthreads();  // w2s dead -> region1 becomes h2 tile
  #pragma unroll
  for (int r = 0; r < 4; ++r) {
    int t = mt * 16 + g * 4 + r;
    double v0 = c0[r] > 0.0 ? c0[r] : 0.0;      // relu(h2)
    double v1 = c1[r] > 0.0 ? c1[r] : 0.0;
    h2t[t * 66 + nt0 * 16 + i15] = v0;
    h2t[t * 66 + nt0 * 16 + 16 + i15] = v1;
  }
  __syncthreads();

  // ---- layer 3 (K=64, 16 MFMA k-steps x 2 N-tiles)
  f64x4 d0, d1;
  {
    double v0 = b3s[nt0 * 16 + i15], v1 = b3s[nt0 * 16 + 16 + i15];
    d0[0] = v0; d0[1] = v0; d0[2] = v0; d0[3] = v0;
    d1[0] = v1; d1[1] = v1; d1[2] = v1; d1[3] = v1;
  }
  #pragma unroll 8
  for (int ks = 0; ks < 16; ++ks) {
    int k = ks * 4 + g;
    double a3 = h2t[(mt * 16 + i15) * 66 + k];
    double b0 = (double)w3s[k * 66 + nt0 * 16 + i15];
    double b1 = (double)w3s[k * 66 + nt0 * 16 + 16 + i15];
    d0 = __builtin_amdgcn_mfma_f64_16x16x4f64(a3, b0, d0, 0, 0, 0);
    d1 = __builtin_amdgcn_mfma_f64_16x16x4f64(a3, b1, d1, 0, 0, 0);
  }
  __syncthreads();  // h2 + w3s dead -> region1 becomes lgT, region2 free
  #pragma unroll
  for (int r = 0; r < 4; ++r) {
    int t = mt * 16 + g * 4 + r;
    int z0 = nt0 * 16 + i15, z1 = z0 + 16;
    lgT[z0 * 66 + t] = d0[r];
    lgT[z1 * 66 + t] = d1[r];
    lg32[(size_t)z0 * T_STEPS + t0 + t] = (float)d0[r];  // L2 merges lines
    lg32[(size_t)z1 * T_STEPS + t0 + t] = (float)d1[r];
  }
  __syncthreads();

  // ---- Phase C1: split global argmax over z (lane = t), first-index ties
  {
    int zb = wv * 8;
    double vm = lgT[zb * 66 + lane];
    int jm = zb;
    #pragma unroll
    for (int zz = 1; zz < 8; ++zz) {
      double v = lgT[(zb + zz) * 66 + lane];
      if (v > vm) { vm = v; jm = zb + zz; }
    }
    pv[wv * 64 + lane] = vm;
    pi[wv * 64 + lane] = (u8)jm;
  }
  __syncthreads();
  double vmax = pv[lane];
  int jmax = pi[lane];
  #pragma unroll
  for (int w = 1; w < 8; ++w) {
    double v = pv[w * 64 + lane];
    int j = pi[w * 64 + lane];
    if (v > vmax) { vmax = v; jmax = j; }  // ascending w keeps smallest z on ties
  }
  double vgap = vmax - 1.0;

  // ---- Phase C2: F[t][z] for this wave's z-slice (uniform-row scans)
  const u32* __restrict__ nbrP = (const u32*)(ws_ro + NBRP_OFF);
  const u8* __restrict__ degs = ws_ro + DEGS_OFF;
  const ull* __restrict__ adjg = (const ull*)(ws_ro + ADJ_OFF);
  #pragma unroll
  for (int zz = 0; zz < 8; ++zz) {
    int z = __builtin_amdgcn_readfirstlane(wv * 8 + zz);
    ull az = adjg[z];                                  // uniform s_load
    int nk4 = __builtin_amdgcn_readfirstlane((int)degs[z]);
    double vn = -1.0e300;
    int jn = 0;
    for (int k4 = 0; k4 < nk4; ++k4) {
      u32 w4 = nbrP[z * 16 + k4];                      // uniform s_load
      #pragma unroll
      for (int b = 0; b < 4; ++b) {
        int j = (w4 >> (b * 8)) & 63;                  // uniform
        double val = lgT[j * 66 + lane];               // uniform row read
        if (val > vn) { vn = val; jn = j; }            // ascending, strict >
      }
    }
    int bit = (int)((az >> jmax) & 1ull);
    int fnb = (vn > vgap) ? jn : ((vn < vgap) ? jmax : (jn < jmax ? jn : jmax));
    F_lds[lane * 68 + z] = (u8)(bit ? jmax : fnb);
  }
  __syncthreads();

  // ---- Phase C3: coalesced ftab write
  u32* fo = (u32*)(ftab + (size_t)t0 * 64);
  #pragma unroll
  for (int r = 0; r < 2; ++r) {
    int i = tid + r * 512;            // 1024 words = 64t x 16 words
    int t = i >> 4, z4 = (i & 15) << 2;
    fo[i] = *(const u32*)&F_lds[t * 68 + z4];
  }

  // ---- Phase C4: compose this wave's chunk table (lane = z)
  int c = blockIdx.x * 8 + wv;
  int cur = lane;
  #pragma unroll
  for (int i = 0; i < CL; ++i) cur = F_lds[(wv * 8 + i) * 68 + cur];
  chunkG[(size_t)c * 64 + lane] = (u8)cur;
}

// ---------------------------------------------------------------------------
// K4: compose SUP_L chunk tables into each super table.
// ---------------------------------------------------------------------------
__global__ void super_compose_kernel(const unsigned char* __restrict__ chunkG,
                                     unsigned char* __restrict__ superS) {
  int lane = threadIdx.x & 63, wv = threadIdx.x >> 6;
  int k = blockIdx.x * 4 + wv;
  int cur = lane;
  #pragma unroll 8
  for (int c = k * SUP_L; c < (k + 1) * SUP_L; ++c) {
    int g = chunkG[(size_t)c * 64 + lane];
    cur = __shfl(g, cur, 64);
  }
  superS[(size_t)k * 64 + lane] = (unsigned char)cur;
}

// ---------------------------------------------------------------------------
// K5: sequential walk over NSUPER super tables (1 wave, LDS-staged).
// ---------------------------------------------------------------------------
__global__ void super_walk_kernel(const unsigned char* __restrict__ superS,
                                  int* __restrict__ supState) {
  __shared__ unsigned char ssup[NSUPER * 64];
  int lane = threadIdx.x;
  for (int i = lane; i < NSUPER * 16; i += 64)
    ((unsigned int*)ssup)[i] = ((const unsigned int*)superS)[i];
  __syncthreads();
  int s = 0;
  if (lane == 0) supState[0] = 0;
  for (int k = 0; k < NSUPER; ++k) {
    int v = ssup[k * 64 + lane];
    s = __shfl(v, s, 64);
    if (lane == 0 && k + 1 < NSUPER) supState[k + 1] = s;
  }
}

// ---------------------------------------------------------------------------
// K6: per-chunk start states — LDS-staged walk.
// ---------------------------------------------------------------------------
__global__ __launch_bounds__(256) void chunk_states_kernel(
    const unsigned char* __restrict__ chunkG,
    const int* __restrict__ supState,
    int* __restrict__ chunkState) {
  __shared__ unsigned char g[4][SUP_L * 64];
  __shared__ int sbuf[4][SUP_L];
  int tid = threadIdx.x, lane = tid & 63, wv = tid >> 6;
  int k = blockIdx.x * 4 + wv;
  const unsigned int* src = (const unsigned int*)(chunkG + (size_t)k * SUP_L * 64);
  unsigned int* dst = (unsigned int*)g[wv];
  #pragma unroll 4
  for (int i = lane; i < SUP_L * 16; i += 64) dst[i] = src[i];
  int s = supState[k];
  for (int c = 0; c < SUP_L; ++c) {
    if (lane == 0) sbuf[wv][c] = s;
    s = g[wv][c * 64 + s];
  }
  chunkState[k * SUP_L + lane] = sbuf[wv][lane];
}

// ---------------------------------------------------------------------------
// K7: finalize — streaming: read lg32 (f32 z-major) + LDS-staged F lookups,
// write out = lg - 1 + A[z_t] fresh each call (no in-place accumulation).
// ---------------------------------------------------------------------------
__global__ __launch_bounds__(256) void finalize_kernel(
    const float* __restrict__ lg32, const unsigned char* __restrict__ ws_ro,
    const int* __restrict__ chunkState, const unsigned char* __restrict__ ftab,
    float* __restrict__ out) {
  __shared__ ull adjs[64];
  __shared__ unsigned char fstage[4][CL * 64];
  int tid = threadIdx.x, lane = tid & 63, wv = tid >> 6;
  if (tid < 64) adjs[tid] = ((const ull*)(ws_ro + ADJ_OFF))[tid];
  __syncthreads();
  int c = blockIdx.x * 4 + wv;
  int s = chunkState[c];
  size_t tb = (size_t)c * CL * 64;

  float lgv[CL];
  #pragma unroll
  for (int i = 0; i < CL; ++i)
    lgv[i] = lg32[(size_t)lane * T_STEPS + c * CL + i];  // 32B contig per lane

  unsigned int* dst = (unsigned int*)fstage[wv];
  const unsigned int* src = (const unsigned int*)(ftab + tb);
  #pragma unroll
  for (int i = lane; i < CL * 16; i += 64) dst[i] = src[i];
  // wave-private LDS; compiler inserts the lgkm wait
  #pragma unroll
  for (int i = 0; i < CL; ++i) {
    int bit = (int)((adjs[s] >> lane) & 1ull);
    out[tb + i * 64 + lane] = bit ? lgv[i] : lgv[i] - 1.0f;
    s = fstage[wv][i * 64 + s];  // uniform broadcast read
  }
}

// ---------------------------------------------------------------------------
extern "C" void kernel_launch(void* const* d_in, const int* in_sizes, int n_in,
                              void* d_out, int out_size, void* d_ws, size_t ws_size,
                              hipStream_t stream) {
  const float* pa    = (const float*)d_in[0];
  const float* times = (const float*)d_in[1];
  // d_in[2] zone_features: unused by the reference
  const int*   edges = (const int*)d_in[3];
  const float* W1    = (const float*)d_in[4];
  const float* b1    = (const float*)d_in[5];
  const float* W2    = (const float*)d_in[6];
  const float* b2    = (const float*)d_in[7];
  const float* W3    = (const float*)d_in[8];
  const float* b3    = (const float*)d_in[9];

  unsigned char* ws = (unsigned char*)d_ws;
  unsigned char* outb = (unsigned char*)d_out;  // scratch until finalize
  float* lg32 = (float*)(ws + LG32_OFF);
  unsigned char* ftab = ws + FTAB_OFF;
  unsigned char* chunkG = outb + CHUNKG_DOUT;
  unsigned char* superS = outb + SUPERS_DOUT;
  int* supState = (int*)(outb + SUPSTATE_DOUT);
  int* chunkState = (int*)(ws + CHUNKSTATE_OFF);

  hipLaunchKernelGGL(prep_kernel, dim3(1), dim3(512), 0, stream,
                     pa, edges, W1, b1, b2, b3, ws);
  hipLaunchKernelGGL(mlp_tables_kernel, dim3(T_STEPS / 64), dim3(512), 0, stream,
                     times, W2, W3, ws, lg32, chunkG, ftab);
  hipLaunchKernelGGL(super_compose_kernel, dim3(NSUPER / 4), dim3(256), 0, stream,
                     chunkG, superS);
  hipLaunchKernelGGL(super_walk_kernel, dim3(1), dim3(64), 0, stream,
                     superS, supState);
  hipLaunchKernelGGL(chunk_states_kernel, dim3(NSUPER / 4), dim3(256), 0, stream,
                     chunkG, supState, chunkState);
  hipLaunchKernelGGL(finalize_kernel, dim3(NCHUNK / 4), dim3(256), 0, stream,
                     lg32, ws, chunkState, ftab, (float*)d_out);
}

// Round 9
// 100.192 us; speedup vs baseline: 2.9032x; 1.0809x over previous
//
#include <hip/hip_runtime.h>

#define T_STEPS 65536
#define NZ 64
#define NH1 128
#define NH2 64
#define NEDGE 512
#define NCHUNK 8192
#define CL 8            // timesteps per chunk (T_STEPS / NCHUNK)
#define NSUPER 128
#define SUP_L 64        // chunks per super (NCHUNK / NSUPER)

// ---- ws layout (bytes). Total need = 140288 + 16MB + 4MB ~= 21.1MB
#define ADJ_OFF        0          // 64 * u64
#define BASE1_OFF      512        // 128 * f64
#define W1T_OFF        1536      // 128 * f64
#define NBRP_OFF       2560      // 64 z * 16 u32 words (4 packed u8 ids each) = 4096
#define DEGS_OFF       6656      // 64 u8: per-z u32-word count (ceil(deg/4))
#define CHUNKSTATE_OFF 6720      // NCHUNK * i32 = 32768 (ends 39488)
#define B2D_OFF        139264    // 64 f64
#define B3D_OFF        139776    // 64 f64
#define LG32_OFF       140288    // 64*T f32 (z-major: lg32[z*T + t]) = 16MB
#define FTAB_OFF       (LG32_OFF + (size_t)T_STEPS * NZ * 4)   // T*64 u8 = 4MB

// ---- d_out used as scratch before finalize overwrites it (deterministic)
#define CHUNKG_DOUT    0          // NCHUNK*64 u8 = 524288
#define SUPERS_DOUT    524288     // NSUPER*64 u8 = 8192

typedef unsigned long long ull;
typedef unsigned int u32;
typedef unsigned char u8;
typedef double f64x4 __attribute__((ext_vector_type(4)));

// ---------------------------------------------------------------------------
// K1: adjacency bitmasks, u32-packed per-z neighbor lists (ascending,
// padded with first-neighbor to word boundary), f64 bias/base precompute.
// ---------------------------------------------------------------------------
__global__ void prep_kernel(const float* __restrict__ pa,
                            const int* __restrict__ edges,
                            const float* __restrict__ W1,
                            const float* __restrict__ b1,
                            const float* __restrict__ b2,
                            const float* __restrict__ b3,
                            unsigned char* ws) {
  ull* adj = (ull*)(ws + ADJ_OFF);
  double* base1 = (double*)(ws + BASE1_OFF);
  double* w1t   = (double*)(ws + W1T_OFF);
  double* b2d = (double*)(ws + B2D_OFF);
  double* b3d = (double*)(ws + B3D_OFF);
  int tid = threadIdx.x;
  if (tid < NZ) adj[tid] = 0ull;
  __syncthreads();
  if (tid < NEDGE) {
    int e0 = edges[tid];
    int e1 = edges[NEDGE + tid];
    atomicOr(&adj[e0], 1ull << e1);
    atomicOr(&adj[e1], 1ull << e0);
  }
  if (tid < NZ) atomicOr(&adj[tid], 1ull << tid);  // self loops
  if (tid < NH1) {
    double acc = (double)b1[tid];
    for (int d = 0; d < 64; ++d)
      acc += (double)pa[d] * (double)W1[d * NH1 + tid];
    base1[tid] = acc;
    w1t[tid] = (double)W1[64 * NH1 + tid];
  }
  if (tid < NH2) b2d[tid] = (double)b2[tid];
  if (tid < NZ)  b3d[tid] = (double)b3[tid];
  __syncthreads();
  if (tid < NZ) {
    ull m = adj[tid];
    u32 wbuf[16];
    #pragma unroll
    for (int i = 0; i < 16; ++i) wbuf[i] = 0u;
    int deg = 0, jfirst = 0;
    while (m) {
      int j = __builtin_ctzll(m);
      m &= m - 1;
      if (deg == 0) jfirst = j;
      wbuf[deg >> 2] |= (u32)j << ((deg & 3) * 8);
      ++deg;
    }
    int padded = (deg + 3) & ~3;
    for (int k = deg; k < padded; ++k)
      wbuf[k >> 2] |= (u32)jfirst << ((k & 3) * 8);
    u32* np = (u32*)(ws + NBRP_OFF) + tid * 16;
    #pragma unroll
    for (int i = 0; i < 16; ++i) np[i] = wbuf[i];
    (ws + DEGS_OFF)[tid] = (u8)(padded >> 2);
  }
}

// ---------------------------------------------------------------------------
// K2 (fused): MFMA-f64 MLP + per-chunk transition tables.
// 512 threads = 8 waves; block owns 64 timesteps.
// LDS = 52736B -> 3 blocks/CU (was 53760 -> 2): b2/b3 accumulator-init
// values read straight from ws (once per wave, L2-served) instead of LDS.
// ---------------------------------------------------------------------------
__global__ __launch_bounds__(512) void mlp_tables_kernel(
    const float* __restrict__ times,
    const float* __restrict__ W2,
    const float* __restrict__ W3,
    const unsigned char* __restrict__ ws_ro,
    float* __restrict__ lg32,
    unsigned char* __restrict__ chunkG,
    unsigned char* __restrict__ ftab) {
  __shared__ double region1[4224];   // 33792B: w2s f32[128][66] -> h2/lgT f64[64][66]
  __shared__ double region2[2112];   // 16896B: w3s f32[64][66] -> {F_lds, pv, pi}
  __shared__ double base1s[NH1], w1ts[NH1];  // 2048B (read 32x per wave)

  float* w2s = (float*)region1;             // [128][66] f32
  float* w3s = (float*)region2;             // [64][66] f32
  double* h2t = region1;                    // [64 t][66] f64
  double* lgT = region1;                    // [64 z][66] f64
  u8* F_lds = (u8*)region2;                 // [64 t][68] u8 = 4352B
  double* pv = (double*)((u8*)region2 + 4352);  // [8][64] f64 = 4096B
  u8* pi = (u8*)region2 + 8448;             // [8][64] u8 = 512B

  const double* __restrict__ b2dg = (const double*)(ws_ro + B2D_OFF);
  const double* __restrict__ b3dg = (const double*)(ws_ro + B3D_OFF);

  int tid = threadIdx.x, lane = tid & 63, wv = tid >> 6;
  int i15 = lane & 15, g = lane >> 4;
  int mt = wv & 3, nt0 = (wv >> 2) * 2;
  int t0 = blockIdx.x * 64;

  // ---- stage weights (f32) + f64 layer-1 constants
  for (int i = tid; i < NH1 * 64; i += 512) w2s[(i >> 6) * 66 + (i & 63)] = W2[i];
  for (int i = tid; i < NH2 * 64; i += 512) w3s[(i >> 6) * 66 + (i & 63)] = W3[i];
  if (tid < NH1) {
    base1s[tid] = ((const double*)(ws_ro + BASE1_OFF))[tid];
    w1ts[tid]   = ((const double*)(ws_ro + W1T_OFF))[tid];
  }
  double tv = (double)times[t0 + mt * 16 + i15];
  // accumulator-init biases straight from global (once per wave)
  double bi20 = b2dg[nt0 * 16 + i15], bi21 = b2dg[nt0 * 16 + 16 + i15];
  double bi30 = b3dg[nt0 * 16 + i15], bi31 = b3dg[nt0 * 16 + 16 + i15];
  __syncthreads();

  // ---- layer 2 (K=128, 32 MFMA k-steps x 2 N-tiles)
  f64x4 c0, c1;
  c0[0] = bi20; c0[1] = bi20; c0[2] = bi20; c0[3] = bi20;
  c1[0] = bi21; c1[1] = bi21; c1[2] = bi21; c1[3] = bi21;
  #pragma unroll 8
  for (int ks = 0; ks < 32; ++ks) {
    int h = ks * 4 + g;
    double a = fma(tv, w1ts[h], base1s[h]);
    a = a > 0.0 ? a : 0.0;                      // h1 = relu(...), exact f64
    double b0 = (double)w2s[h * 66 + nt0 * 16 + i15];
    double b1 = (double)w2s[h * 66 + nt0 * 16 + 16 + i15];
    c0 = __builtin_amdgcn_mfma_f64_16x16x4f64(a, b0, c0, 0, 0, 0);
    c1 = __builtin_amdgcn_mfma_f64_16x16x4f64(a, b1, c1, 0, 0, 0);
  }
  __syncthreads();  // w2s dead -> region1 becomes h2 tile
  #pragma unroll
  for (int r = 0; r < 4; ++r) {
    int t = mt * 16 + g * 4 + r;
    double v0 = c0[r] > 0.0 ? c0[r] : 0.0;      // relu(h2)
    double v1 = c1[r] > 0.0 ? c1[r] : 0.0;
    h2t[t * 66 + nt0 * 16 + i15] = v0;
    h2t[t * 66 + nt0 * 16 + 16 + i15] = v1;
  }
  __syncthreads();

  // ---- layer 3 (K=64, 16 MFMA k-steps x 2 N-tiles)
  f64x4 d0, d1;
  d0[0] = bi30; d0[1] = bi30; d0[2] = bi30; d0[3] = bi30;
  d1[0] = bi31; d1[1] = bi31; d1[2] = bi31; d1[3] = bi31;
  #pragma unroll 8
  for (int ks = 0; ks < 16; ++ks) {
    int k = ks * 4 + g;
    double a3 = h2t[(mt * 16 + i15) * 66 + k];
    double b0 = (double)w3s[k * 66 + nt0 * 16 + i15];
    double b1 = (double)w3s[k * 66 + nt0 * 16 + 16 + i15];
    d0 = __builtin_amdgcn_mfma_f64_16x16x4f64(a3, b0, d0, 0, 0, 0);
    d1 = __builtin_amdgcn_mfma_f64_16x16x4f64(a3, b1, d1, 0, 0, 0);
  }
  __syncthreads();  // h2 + w3s dead -> region1 becomes lgT, region2 free
  #pragma unroll
  for (int r = 0; r < 4; ++r) {
    int t = mt * 16 + g * 4 + r;
    int z0 = nt0 * 16 + i15, z1 = z0 + 16;
    lgT[z0 * 66 + t] = d0[r];
    lgT[z1 * 66 + t] = d1[r];
    lg32[(size_t)z0 * T_STEPS + t0 + t] = (float)d0[r];  // L2 merges lines
    lg32[(size_t)z1 * T_STEPS + t0 + t] = (float)d1[r];
  }
  __syncthreads();

  // ---- Phase C1: split global argmax over z (lane = t), first-index ties
  {
    int zb = wv * 8;
    double vm = lgT[zb * 66 + lane];
    int jm = zb;
    #pragma unroll
    for (int zz = 1; zz < 8; ++zz) {
      double v = lgT[(zb + zz) * 66 + lane];
      if (v > vm) { vm = v; jm = zb + zz; }
    }
    pv[wv * 64 + lane] = vm;
    pi[wv * 64 + lane] = (u8)jm;
  }
  __syncthreads();
  double vmax = pv[lane];
  int jmax = pi[lane];
  #pragma unroll
  for (int w = 1; w < 8; ++w) {
    double v = pv[w * 64 + lane];
    int j = pi[w * 64 + lane];
    if (v > vmax) { vmax = v; jmax = j; }  // ascending w keeps smallest z on ties
  }
  double vgap = vmax - 1.0;

  // ---- Phase C2: F[t][z] for this wave's z-slice (uniform-row scans)
  const u32* __restrict__ nbrP = (const u32*)(ws_ro + NBRP_OFF);
  const u8* __restrict__ degs = ws_ro + DEGS_OFF;
  const ull* __restrict__ adjg = (const ull*)(ws_ro + ADJ_OFF);
  #pragma unroll
  for (int zz = 0; zz < 8; ++zz) {
    int z = __builtin_amdgcn_readfirstlane(wv * 8 + zz);
    ull az = adjg[z];                                  // uniform s_load
    int nk4 = __builtin_amdgcn_readfirstlane((int)degs[z]);
    double vn = -1.0e300;
    int jn = 0;
    for (int k4 = 0; k4 < nk4; ++k4) {
      u32 w4 = nbrP[z * 16 + k4];                      // uniform s_load
      #pragma unroll
      for (int b = 0; b < 4; ++b) {
        int j = (w4 >> (b * 8)) & 63;                  // uniform
        double val = lgT[j * 66 + lane];               // uniform row read
        if (val > vn) { vn = val; jn = j; }            // ascending, strict >
      }
    }
    int bit = (int)((az >> jmax) & 1ull);
    int fnb = (vn > vgap) ? jn : ((vn < vgap) ? jmax : (jn < jmax ? jn : jmax));
    F_lds[lane * 68 + z] = (u8)(bit ? jmax : fnb);
  }
  __syncthreads();

  // ---- Phase C3: coalesced ftab write
  u32* fo = (u32*)(ftab + (size_t)t0 * 64);
  #pragma unroll
  for (int r = 0; r < 2; ++r) {
    int i = tid + r * 512;            // 1024 words = 64t x 16 words
    int t = i >> 4, z4 = (i & 15) << 2;
    fo[i] = *(const u32*)&F_lds[t * 68 + z4];
  }

  // ---- Phase C4: compose this wave's chunk table (lane = z)
  int c = blockIdx.x * 8 + wv;
  int cur = lane;
  #pragma unroll
  for (int i = 0; i < CL; ++i) cur = F_lds[(wv * 8 + i) * 68 + cur];
  chunkG[(size_t)c * 64 + lane] = (u8)cur;
}

// ---------------------------------------------------------------------------
// K4: compose SUP_L chunk tables into each super table.
// ---------------------------------------------------------------------------
__global__ void super_compose_kernel(const unsigned char* __restrict__ chunkG,
                                     unsigned char* __restrict__ superS) {
  int lane = threadIdx.x & 63, wv = threadIdx.x >> 6;
  int k = blockIdx.x * 4 + wv;
  int cur = lane;
  #pragma unroll 8
  for (int c = k * SUP_L; c < (k + 1) * SUP_L; ++c) {
    int g = chunkG[(size_t)c * 64 + lane];
    cur = __shfl(g, cur, 64);
  }
  superS[(size_t)k * 64 + lane] = (unsigned char)cur;
}

// ---------------------------------------------------------------------------
// K6: per-chunk start states. Now also absorbs the super-walk: each block
// stages all superS into LDS and each wave walks supers 0..k-1 (uniform
// dependent u8 chain, <=127 hops) to get its super's entry state; then the
// per-chunk LDS-staged walk as before. (super_walk_kernel launch deleted.)
// ---------------------------------------------------------------------------
__global__ __launch_bounds__(256) void chunk_states_kernel(
    const unsigned char* __restrict__ chunkG,
    const unsigned char* __restrict__ superS,
    int* __restrict__ chunkState) {
  __shared__ unsigned char ssup[NSUPER * 64];  // 8KB
  __shared__ unsigned char g[4][SUP_L * 64];   // 16KB
  __shared__ int sbuf[4][SUP_L];
  int tid = threadIdx.x, lane = tid & 63, wv = tid >> 6;
  int k = blockIdx.x * 4 + wv;
  for (int i = tid; i < NSUPER * 16; i += 256)
    ((u32*)ssup)[i] = ((const u32*)superS)[i];
  const unsigned int* src = (const unsigned int*)(chunkG + (size_t)k * SUP_L * 64);
  unsigned int* dst = (unsigned int*)g[wv];
  #pragma unroll 4
  for (int i = lane; i < SUP_L * 16; i += 64) dst[i] = src[i];
  __syncthreads();
  // walk supers 0..k-1 (redundant per wave; uniform across lanes)
  int s = 0;
  for (int i = 0; i < k; ++i) s = ssup[i * 64 + s];
  // per-chunk walk within this super
  for (int c = 0; c < SUP_L; ++c) {
    if (lane == 0) sbuf[wv][c] = s;
    s = g[wv][c * 64 + s];
  }
  chunkState[k * SUP_L + lane] = sbuf[wv][lane];
}

// ---------------------------------------------------------------------------
// K7: finalize — streaming: read lg32 (f32 z-major) + LDS-staged F lookups,
// write out = lg - 1 + A[z_t] fresh each call.
// ---------------------------------------------------------------------------
__global__ __launch_bounds__(256) void finalize_kernel(
    const float* __restrict__ lg32, const unsigned char* __restrict__ ws_ro,
    const int* __restrict__ chunkState, const unsigned char* __restrict__ ftab,
    float* __restrict__ out) {
  __shared__ ull adjs[64];
  __shared__ unsigned char fstage[4][CL * 64];
  int tid = threadIdx.x, lane = tid & 63, wv = tid >> 6;
  if (tid < 64) adjs[tid] = ((const ull*)(ws_ro + ADJ_OFF))[tid];
  __syncthreads();
  int c = blockIdx.x * 4 + wv;
  int s = chunkState[c];
  size_t tb = (size_t)c * CL * 64;

  float lgv[CL];
  #pragma unroll
  for (int i = 0; i < CL; ++i)
    lgv[i] = lg32[(size_t)lane * T_STEPS + c * CL + i];  // 32B contig per lane

  unsigned int* dst = (unsigned int*)fstage[wv];
  const unsigned int* src = (const unsigned int*)(ftab + tb);
  #pragma unroll
  for (int i = lane; i < CL * 16; i += 64) dst[i] = src[i];
  // wave-private LDS; compiler inserts the lgkm wait
  #pragma unroll
  for (int i = 0; i < CL; ++i) {
    int bit = (int)((adjs[s] >> lane) & 1ull);
    out[tb + i * 64 + lane] = bit ? lgv[i] : lgv[i] - 1.0f;
    s = fstage[wv][i * 64 + s];  // uniform broadcast read
  }
}

// ---------------------------------------------------------------------------
extern "C" void kernel_launch(void* const* d_in, const int* in_sizes, int n_in,
                              void* d_out, int out_size, void* d_ws, size_t ws_size,
                              hipStream_t stream) {
  const float* pa    = (const float*)d_in[0];
  const float* times = (const float*)d_in[1];
  // d_in[2] zone_features: unused by the reference
  const int*   edges = (const int*)d_in[3];
  const float* W1    = (const float*)d_in[4];
  const float* b1    = (const float*)d_in[5];
  const float* W2    = (const float*)d_in[6];
  const float* b2    = (const float*)d_in[7];
  const float* W3    = (const float*)d_in[8];
  const float* b3    = (const float*)d_in[9];

  unsigned char* ws = (unsigned char*)d_ws;
  unsigned char* outb = (unsigned char*)d_out;  // scratch until finalize
  float* lg32 = (float*)(ws + LG32_OFF);
  unsigned char* ftab = ws + FTAB_OFF;
  unsigned char* chunkG = outb + CHUNKG_DOUT;
  unsigned char* superS = outb + SUPERS_DOUT;
  int* chunkState = (int*)(ws + CHUNKSTATE_OFF);

  hipLaunchKernelGGL(prep_kernel, dim3(1), dim3(512), 0, stream,
                     pa, edges, W1, b1, b2, b3, ws);
  hipLaunchKernelGGL(mlp_tables_kernel, dim3(T_STEPS / 64), dim3(512), 0, stream,
                     times, W2, W3, ws, lg32, chunkG, ftab);
  hipLaunchKernelGGL(super_compose_kernel, dim3(NSUPER / 4), dim3(256), 0, stream,
                     chunkG, superS);
  hipLaunchKernelGGL(chunk_states_kernel, dim3(NSUPER / 4), dim3(256), 0, stream,
                     chunkG, superS, chunkState);
  hipLaunchKernelGGL(finalize_kernel, dim3(NCHUNK / 4), dim3(256), 0, stream,
                     lg32, ws, chunkState, ftab, (float*)d_out);
}

// Round 10
// 91.128 us; speedup vs baseline: 3.1920x; 1.0995x over previous
//
#include <hip/hip_runtime.h>

#define T_STEPS 65536
#define NZ 64
#define NH1 128
#define NH2 64
#define NEDGE 512
#define NCHUNK 8192
#define CL 8            // timesteps per chunk (T_STEPS / NCHUNK)
#define NSUPER 128
#define SUP_L 64        // chunks per super (NCHUNK / NSUPER)

// ---- ws layout (bytes). Total need = 140288 + 16MB + 4MB ~= 21.1MB
#define ADJ_OFF        0          // 64 * u64
#define BASE1_OFF      512        // 128 * f64
#define W1T_OFF        1536      // 128 * f64
#define NBRP_OFF       2560      // 64 z * 16 u32 words (4 packed u8 ids each) = 4096
#define DEGS_OFF       6656      // 64 u8: per-z u32-word count (ceil(deg/4))
#define CHUNKSTATE_OFF 6720      // NCHUNK * i32 = 32768 (ends 39488)
#define B2D_OFF        139264    // 64 f64
#define B3D_OFF        139776    // 64 f64
#define LG32_OFF       140288    // 64*T f32 (z-major: lg32[z*T + t]) = 16MB
#define FTAB_OFF       (LG32_OFF + (size_t)T_STEPS * NZ * 4)   // T*64 u8 = 4MB

// ---- d_out used as scratch before finalize overwrites it (deterministic)
#define CHUNKG_DOUT    0          // NCHUNK*64 u8 = 524288
#define SUPERS_DOUT    524288     // NSUPER*64 u8 = 8192

typedef unsigned long long ull;
typedef unsigned int u32;
typedef unsigned char u8;
typedef double f64x4 __attribute__((ext_vector_type(4)));

// ---------------------------------------------------------------------------
// K1: adjacency bitmasks, u32-packed per-z neighbor lists (ascending,
// padded with first-neighbor to word boundary), f64 bias/base precompute.
// ---------------------------------------------------------------------------
__global__ void prep_kernel(const float* __restrict__ pa,
                            const int* __restrict__ edges,
                            const float* __restrict__ W1,
                            const float* __restrict__ b1,
                            const float* __restrict__ b2,
                            const float* __restrict__ b3,
                            unsigned char* ws) {
  ull* adj = (ull*)(ws + ADJ_OFF);
  double* base1 = (double*)(ws + BASE1_OFF);
  double* w1t   = (double*)(ws + W1T_OFF);
  double* b2d = (double*)(ws + B2D_OFF);
  double* b3d = (double*)(ws + B3D_OFF);
  int tid = threadIdx.x;
  if (tid < NZ) adj[tid] = 0ull;
  __syncthreads();
  if (tid < NEDGE) {
    int e0 = edges[tid];
    int e1 = edges[NEDGE + tid];
    atomicOr(&adj[e0], 1ull << e1);
    atomicOr(&adj[e1], 1ull << e0);
  }
  if (tid < NZ) atomicOr(&adj[tid], 1ull << tid);  // self loops
  if (tid < NH1) {
    double acc = (double)b1[tid];
    for (int d = 0; d < 64; ++d)
      acc += (double)pa[d] * (double)W1[d * NH1 + tid];
    base1[tid] = acc;
    w1t[tid] = (double)W1[64 * NH1 + tid];
  }
  if (tid < NH2) b2d[tid] = (double)b2[tid];
  if (tid < NZ)  b3d[tid] = (double)b3[tid];
  __syncthreads();
  if (tid < NZ) {
    ull m = adj[tid];
    u32 wbuf[16];
    #pragma unroll
    for (int i = 0; i < 16; ++i) wbuf[i] = 0u;
    int deg = 0, jfirst = 0;
    while (m) {
      int j = __builtin_ctzll(m);
      m &= m - 1;
      if (deg == 0) jfirst = j;
      wbuf[deg >> 2] |= (u32)j << ((deg & 3) * 8);
      ++deg;
    }
    int padded = (deg + 3) & ~3;
    for (int k = deg; k < padded; ++k)
      wbuf[k >> 2] |= (u32)jfirst << ((k & 3) * 8);
    u32* np = (u32*)(ws + NBRP_OFF) + tid * 16;
    #pragma unroll
    for (int i = 0; i < 16; ++i) np[i] = wbuf[i];
    (ws + DEGS_OFF)[tid] = (u8)(padded >> 2);
  }
}

// ---------------------------------------------------------------------------
// K2 (fused): MFMA-f64 MLP + per-chunk transition tables.
// 512 threads = 8 waves; block owns 64 timesteps.
// lg32 store moved out of the MFMA epilogue (was a 256KB-strided per-lane
// scatter: up to 64 transactions per store) into phase C1a, where wave wv
// reads its 8 lgT rows with lane=t anyway -> coalesced 256B stores.
// ---------------------------------------------------------------------------
__global__ __launch_bounds__(512) void mlp_tables_kernel(
    const float* __restrict__ times,
    const float* __restrict__ W2,
    const float* __restrict__ W3,
    const unsigned char* __restrict__ ws_ro,
    float* __restrict__ lg32,
    unsigned char* __restrict__ chunkG,
    unsigned char* __restrict__ ftab) {
  __shared__ double region1[4224];   // 33792B: w2s f32[128][66] -> h2/lgT f64[64][66]
  __shared__ double region2[2112];   // 16896B: w3s f32[64][66] -> {F_lds, pv, pi}
  __shared__ double base1s[NH1], w1ts[NH1];  // 2048B (read 32x per wave)

  float* w2s = (float*)region1;             // [128][66] f32
  float* w3s = (float*)region2;             // [64][66] f32
  double* h2t = region1;                    // [64 t][66] f64
  double* lgT = region1;                    // [64 z][66] f64
  u8* F_lds = (u8*)region2;                 // [64 t][68] u8 = 4352B
  double* pv = (double*)((u8*)region2 + 4352);  // [8][64] f64 = 4096B
  u8* pi = (u8*)region2 + 8448;             // [8][64] u8 = 512B

  const double* __restrict__ b2dg = (const double*)(ws_ro + B2D_OFF);
  const double* __restrict__ b3dg = (const double*)(ws_ro + B3D_OFF);

  int tid = threadIdx.x, lane = tid & 63, wv = tid >> 6;
  int i15 = lane & 15, g = lane >> 4;
  int mt = wv & 3, nt0 = (wv >> 2) * 2;
  int t0 = blockIdx.x * 64;

  // ---- stage weights (f32) + f64 layer-1 constants
  for (int i = tid; i < NH1 * 64; i += 512) w2s[(i >> 6) * 66 + (i & 63)] = W2[i];
  for (int i = tid; i < NH2 * 64; i += 512) w3s[(i >> 6) * 66 + (i & 63)] = W3[i];
  if (tid < NH1) {
    base1s[tid] = ((const double*)(ws_ro + BASE1_OFF))[tid];
    w1ts[tid]   = ((const double*)(ws_ro + W1T_OFF))[tid];
  }
  double tv = (double)times[t0 + mt * 16 + i15];
  // accumulator-init biases straight from global (once per wave)
  double bi20 = b2dg[nt0 * 16 + i15], bi21 = b2dg[nt0 * 16 + 16 + i15];
  double bi30 = b3dg[nt0 * 16 + i15], bi31 = b3dg[nt0 * 16 + 16 + i15];
  __syncthreads();

  // ---- layer 2 (K=128, 32 MFMA k-steps x 2 N-tiles)
  f64x4 c0, c1;
  c0[0] = bi20; c0[1] = bi20; c0[2] = bi20; c0[3] = bi20;
  c1[0] = bi21; c1[1] = bi21; c1[2] = bi21; c1[3] = bi21;
  #pragma unroll 8
  for (int ks = 0; ks < 32; ++ks) {
    int h = ks * 4 + g;
    double a = fma(tv, w1ts[h], base1s[h]);
    a = a > 0.0 ? a : 0.0;                      // h1 = relu(...), exact f64
    double b0 = (double)w2s[h * 66 + nt0 * 16 + i15];
    double b1 = (double)w2s[h * 66 + nt0 * 16 + 16 + i15];
    c0 = __builtin_amdgcn_mfma_f64_16x16x4f64(a, b0, c0, 0, 0, 0);
    c1 = __builtin_amdgcn_mfma_f64_16x16x4f64(a, b1, c1, 0, 0, 0);
  }
  __syncthreads();  // w2s dead -> region1 becomes h2 tile
  #pragma unroll
  for (int r = 0; r < 4; ++r) {
    int t = mt * 16 + g * 4 + r;
    double v0 = c0[r] > 0.0 ? c0[r] : 0.0;      // relu(h2)
    double v1 = c1[r] > 0.0 ? c1[r] : 0.0;
    h2t[t * 66 + nt0 * 16 + i15] = v0;
    h2t[t * 66 + nt0 * 16 + 16 + i15] = v1;
  }
  __syncthreads();

  // ---- layer 3 (K=64, 16 MFMA k-steps x 2 N-tiles)
  f64x4 d0, d1;
  d0[0] = bi30; d0[1] = bi30; d0[2] = bi30; d0[3] = bi30;
  d1[0] = bi31; d1[1] = bi31; d1[2] = bi31; d1[3] = bi31;
  #pragma unroll 8
  for (int ks = 0; ks < 16; ++ks) {
    int k = ks * 4 + g;
    double a3 = h2t[(mt * 16 + i15) * 66 + k];
    double b0 = (double)w3s[k * 66 + nt0 * 16 + i15];
    double b1 = (double)w3s[k * 66 + nt0 * 16 + 16 + i15];
    d0 = __builtin_amdgcn_mfma_f64_16x16x4f64(a3, b0, d0, 0, 0, 0);
    d1 = __builtin_amdgcn_mfma_f64_16x16x4f64(a3, b1, d1, 0, 0, 0);
  }
  __syncthreads();  // h2 + w3s dead -> region1 becomes lgT, region2 free
  #pragma unroll
  for (int r = 0; r < 4; ++r) {
    int t = mt * 16 + g * 4 + r;
    int z0 = nt0 * 16 + i15, z1 = z0 + 16;
    lgT[z0 * 66 + t] = d0[r];
    lgT[z1 * 66 + t] = d1[r];
  }
  __syncthreads();

  // ---- Phase C1a + coalesced lg32 store: wave wv owns z rows [8wv,8wv+8)
  // (lane = t). Row read serves BOTH the f32 store (256B coalesced) and the
  // partial argmax (ascending z, strict > keeps first index).
  {
    int zb = wv * 8;
    double vm = lgT[zb * 66 + lane];
    int jm = zb;
    lg32[(size_t)zb * T_STEPS + t0 + lane] = (float)vm;
    #pragma unroll
    for (int zz = 1; zz < 8; ++zz) {
      double v = lgT[(zb + zz) * 66 + lane];
      lg32[(size_t)(zb + zz) * T_STEPS + t0 + lane] = (float)v;
      if (v > vm) { vm = v; jm = zb + zz; }
    }
    pv[wv * 64 + lane] = vm;
    pi[wv * 64 + lane] = (u8)jm;
  }
  __syncthreads();
  double vmax = pv[lane];
  int jmax = pi[lane];
  #pragma unroll
  for (int w = 1; w < 8; ++w) {
    double v = pv[w * 64 + lane];
    int j = pi[w * 64 + lane];
    if (v > vmax) { vmax = v; jmax = j; }  // ascending w keeps smallest z on ties
  }
  double vgap = vmax - 1.0;

  // ---- Phase C2: F[t][z] for this wave's z-slice (uniform-row scans)
  const u32* __restrict__ nbrP = (const u32*)(ws_ro + NBRP_OFF);
  const u8* __restrict__ degs = ws_ro + DEGS_OFF;
  const ull* __restrict__ adjg = (const ull*)(ws_ro + ADJ_OFF);
  #pragma unroll
  for (int zz = 0; zz < 8; ++zz) {
    int z = __builtin_amdgcn_readfirstlane(wv * 8 + zz);
    ull az = adjg[z];                                  // uniform s_load
    int nk4 = __builtin_amdgcn_readfirstlane((int)degs[z]);
    double vn = -1.0e300;
    int jn = 0;
    for (int k4 = 0; k4 < nk4; ++k4) {
      u32 w4 = nbrP[z * 16 + k4];                      // uniform s_load
      #pragma unroll
      for (int b = 0; b < 4; ++b) {
        int j = (w4 >> (b * 8)) & 63;                  // uniform
        double val = lgT[j * 66 + lane];               // uniform row read
        if (val > vn) { vn = val; jn = j; }            // ascending, strict >
      }
    }
    int bit = (int)((az >> jmax) & 1ull);
    int fnb = (vn > vgap) ? jn : ((vn < vgap) ? jmax : (jn < jmax ? jn : jmax));
    F_lds[lane * 68 + z] = (u8)(bit ? jmax : fnb);
  }
  __syncthreads();

  // ---- Phase C3: coalesced ftab write
  u32* fo = (u32*)(ftab + (size_t)t0 * 64);
  #pragma unroll
  for (int r = 0; r < 2; ++r) {
    int i = tid + r * 512;            // 1024 words = 64t x 16 words
    int t = i >> 4, z4 = (i & 15) << 2;
    fo[i] = *(const u32*)&F_lds[t * 68 + z4];
  }

  // ---- Phase C4: compose this wave's chunk table (lane = z)
  int c = blockIdx.x * 8 + wv;
  int cur = lane;
  #pragma unroll
  for (int i = 0; i < CL; ++i) cur = F_lds[(wv * 8 + i) * 68 + cur];
  chunkG[(size_t)c * 64 + lane] = (u8)cur;
}

// ---------------------------------------------------------------------------
// K4: compose SUP_L chunk tables into each super table. LDS-staged:
// coalesced u32 loads break the 64-deep L2-load dependency chain; the
// compose chain is then shfl-to-shfl (~35cy/hop).
// ---------------------------------------------------------------------------
__global__ __launch_bounds__(256) void super_compose_kernel(
    const unsigned char* __restrict__ chunkG,
    unsigned char* __restrict__ superS) {
  __shared__ u8 g[4][SUP_L * 64];  // 16KB
  int tid = threadIdx.x, lane = tid & 63, wv = tid >> 6;
  int k = blockIdx.x * 4 + wv;
  const u32* src = (const u32*)(chunkG + (size_t)k * SUP_L * 64);
  u32* dst = (u32*)g[wv];
  #pragma unroll 4
  for (int i = lane; i < SUP_L * 16; i += 64) dst[i] = src[i];
  // wave-private LDS region; compiler orders the dependent reads
  int cur = lane;
  #pragma unroll 8
  for (int c = 0; c < SUP_L; ++c) {
    int gg = g[wv][c * 64 + lane];
    cur = __shfl(gg, cur, 64);
  }
  superS[(size_t)k * 64 + lane] = (u8)cur;
}

// ---------------------------------------------------------------------------
// K6: per-chunk start states (absorbs the super walk).
// ---------------------------------------------------------------------------
__global__ __launch_bounds__(256) void chunk_states_kernel(
    const unsigned char* __restrict__ chunkG,
    const unsigned char* __restrict__ superS,
    int* __restrict__ chunkState) {
  __shared__ unsigned char ssup[NSUPER * 64];  // 8KB
  __shared__ unsigned char g[4][SUP_L * 64];   // 16KB
  __shared__ int sbuf[4][SUP_L];
  int tid = threadIdx.x, lane = tid & 63, wv = tid >> 6;
  int k = blockIdx.x * 4 + wv;
  for (int i = tid; i < NSUPER * 16; i += 256)
    ((u32*)ssup)[i] = ((const u32*)superS)[i];
  const unsigned int* src = (const unsigned int*)(chunkG + (size_t)k * SUP_L * 64);
  unsigned int* dst = (unsigned int*)g[wv];
  #pragma unroll 4
  for (int i = lane; i < SUP_L * 16; i += 64) dst[i] = src[i];
  __syncthreads();
  // walk supers 0..k-1 (redundant per wave; uniform across lanes)
  int s = 0;
  for (int i = 0; i < k; ++i) s = ssup[i * 64 + s];
  // per-chunk walk within this super
  for (int c = 0; c < SUP_L; ++c) {
    if (lane == 0) sbuf[wv][c] = s;
    s = g[wv][c * 64 + s];
  }
  chunkState[k * SUP_L + lane] = sbuf[wv][lane];
}

// ---------------------------------------------------------------------------
// K7: finalize — streaming: read lg32 (f32 z-major) + LDS-staged F lookups,
// write out = lg - 1 + A[z_t] fresh each call.
// ---------------------------------------------------------------------------
__global__ __launch_bounds__(256) void finalize_kernel(
    const float* __restrict__ lg32, const unsigned char* __restrict__ ws_ro,
    const int* __restrict__ chunkState, const unsigned char* __restrict__ ftab,
    float* __restrict__ out) {
  __shared__ ull adjs[64];
  __shared__ unsigned char fstage[4][CL * 64];
  int tid = threadIdx.x, lane = tid & 63, wv = tid >> 6;
  if (tid < 64) adjs[tid] = ((const ull*)(ws_ro + ADJ_OFF))[tid];
  __syncthreads();
  int c = blockIdx.x * 4 + wv;
  int s = chunkState[c];
  size_t tb = (size_t)c * CL * 64;

  float lgv[CL];
  #pragma unroll
  for (int i = 0; i < CL; ++i)
    lgv[i] = lg32[(size_t)lane * T_STEPS + c * CL + i];  // 32B contig per lane

  unsigned int* dst = (unsigned int*)fstage[wv];
  const unsigned int* src = (const unsigned int*)(ftab + tb);
  #pragma unroll
  for (int i = lane; i < CL * 16; i += 64) dst[i] = src[i];
  // wave-private LDS; compiler inserts the lgkm wait
  #pragma unroll
  for (int i = 0; i < CL; ++i) {
    int bit = (int)((adjs[s] >> lane) & 1ull);
    out[tb + i * 64 + lane] = bit ? lgv[i] : lgv[i] - 1.0f;
    s = fstage[wv][i * 64 + s];  // uniform broadcast read
  }
}

// ---------------------------------------------------------------------------
extern "C" void kernel_launch(void* const* d_in, const int* in_sizes, int n_in,
                              void* d_out, int out_size, void* d_ws, size_t ws_size,
                              hipStream_t stream) {
  const float* pa    = (const float*)d_in[0];
  const float* times = (const float*)d_in[1];
  // d_in[2] zone_features: unused by the reference
  const int*   edges = (const int*)d_in[3];
  const float* W1    = (const float*)d_in[4];
  const float* b1    = (const float*)d_in[5];
  const float* W2    = (const float*)d_in[6];
  const float* b2    = (const float*)d_in[7];
  const float* W3    = (const float*)d_in[8];
  const float* b3    = (const float*)d_in[9];

  unsigned char* ws = (unsigned char*)d_ws;
  unsigned char* outb = (unsigned char*)d_out;  // scratch until finalize
  float* lg32 = (float*)(ws + LG32_OFF);
  unsigned char* ftab = ws + FTAB_OFF;
  unsigned char* chunkG = outb + CHUNKG_DOUT;
  unsigned char* superS = outb + SUPERS_DOUT;
  int* chunkState = (int*)(ws + CHUNKSTATE_OFF);

  hipLaunchKernelGGL(prep_kernel, dim3(1), dim3(512), 0, stream,
                     pa, edges, W1, b1, b2, b3, ws);
  hipLaunchKernelGGL(mlp_tables_kernel, dim3(T_STEPS / 64), dim3(512), 0, stream,
                     times, W2, W3, ws, lg32, chunkG, ftab);
  hipLaunchKernelGGL(super_compose_kernel, dim3(NSUPER / 4), dim3(256), 0, stream,
                     chunkG, superS);
  hipLaunchKernelGGL(chunk_states_kernel, dim3(NSUPER / 4), dim3(256), 0, stream,
                     chunkG, superS, chunkState);
  hipLaunchKernelGGL(finalize_kernel, dim3(NCHUNK / 4), dim3(256), 0, stream,
                     lg32, ws, chunkState, ftab, (float*)d_out);
}

// Round 12
// 83.908 us; speedup vs baseline: 3.4666x; 1.0860x over previous
//
#include <hip/hip_runtime.h>

#define T_STEPS 65536
#define NZ 64
#define NH1 128
#define NH2 64
#define NEDGE 512
#define NCHUNK 8192
#define CL 8            // timesteps per chunk (T_STEPS / NCHUNK)
#define NSUPER 128
#define SUP_L 64        // chunks per super (NCHUNK / NSUPER)

// ---- ws layout (bytes). Total ~21.2MB (proven ws >= 33.7MB in rounds 2-6)
#define ADJ_OFF        0          // 64 * u64
#define BASE1_OFF      512        // 128 * f64
#define W1T_OFF        1536      // 128 * f64
#define NBRP_OFF       2560      // 64 z * 16 u32 words (4 packed u8 ids each) = 4096
#define DEGS_OFF       6656      // 64 u8: per-z u32-word count (ceil(deg/4))
#define B2D_OFF        139264    // 64 f64
#define B3D_OFF        139776    // 64 f64
#define LG32_OFF       140288    // 64*T f32 (z-major: lg32[z*T + t]) = 16MB
#define FTAB_OFF       (LG32_OFF + (size_t)T_STEPS * NZ * 4)   // T*64 u8 = 4MB
#define CHUNKG_WS      (FTAB_OFF + (size_t)T_STEPS * NZ)       // 512KB
#define SUPERS_WS      (CHUNKG_WS + (size_t)NCHUNK * 64)       // 8KB

typedef unsigned long long ull;
typedef unsigned int u32;
typedef unsigned char u8;
typedef double f64x4 __attribute__((ext_vector_type(4)));

// ---------------------------------------------------------------------------
// K1: adjacency bitmasks, u32-packed per-z neighbor lists (ascending,
// padded with first-neighbor to word boundary), f64 bias/base precompute.
// ---------------------------------------------------------------------------
__global__ void prep_kernel(const float* __restrict__ pa,
                            const int* __restrict__ edges,
                            const float* __restrict__ W1,
                            const float* __restrict__ b1,
                            const float* __restrict__ b2,
                            const float* __restrict__ b3,
                            unsigned char* ws) {
  ull* adj = (ull*)(ws + ADJ_OFF);
  double* base1 = (double*)(ws + BASE1_OFF);
  double* w1t   = (double*)(ws + W1T_OFF);
  double* b2d = (double*)(ws + B2D_OFF);
  double* b3d = (double*)(ws + B3D_OFF);
  int tid = threadIdx.x;
  if (tid < NZ) adj[tid] = 0ull;
  __syncthreads();
  if (tid < NEDGE) {
    int e0 = edges[tid];
    int e1 = edges[NEDGE + tid];
    atomicOr(&adj[e0], 1ull << e1);
    atomicOr(&adj[e1], 1ull << e0);
  }
  if (tid < NZ) atomicOr(&adj[tid], 1ull << tid);  // self loops
  if (tid < NH1) {
    double acc = (double)b1[tid];
    for (int d = 0; d < 64; ++d)
      acc += (double)pa[d] * (double)W1[d * NH1 + tid];
    base1[tid] = acc;
    w1t[tid] = (double)W1[64 * NH1 + tid];
  }
  if (tid < NH2) b2d[tid] = (double)b2[tid];
  if (tid < NZ)  b3d[tid] = (double)b3[tid];
  __syncthreads();
  if (tid < NZ) {
    ull m = adj[tid];
    u32 wbuf[16];
    #pragma unroll
    for (int i = 0; i < 16; ++i) wbuf[i] = 0u;
    int deg = 0, jfirst = 0;
    while (m) {
      int j = __builtin_ctzll(m);
      m &= m - 1;
      if (deg == 0) jfirst = j;
      wbuf[deg >> 2] |= (u32)j << ((deg & 3) * 8);
      ++deg;
    }
    int padded = (deg + 3) & ~3;
    for (int k = deg; k < padded; ++k)
      wbuf[k >> 2] |= (u32)jfirst << ((k & 3) * 8);
    u32* np = (u32*)(ws + NBRP_OFF) + tid * 16;
    #pragma unroll
    for (int i = 0; i < 16; ++i) np[i] = wbuf[i];
    (ws + DEGS_OFF)[tid] = (u8)(padded >> 2);
  }
}

// ---------------------------------------------------------------------------
// K2 (fused): MFMA-f64 MLP + per-chunk transition tables.
// 512 threads = 8 waves; block owns 64 timesteps. LDS caps at 3 blocks/CU
// (6 waves/SIMD) -> launch_bounds(512,6) raises VGPR cap to ~85 at the same
// occupancy, giving the scheduler batching headroom.
// ---------------------------------------------------------------------------
__global__ __launch_bounds__(512, 6) void mlp_tables_kernel(
    const float* __restrict__ times,
    const float* __restrict__ W2,
    const float* __restrict__ W3,
    const unsigned char* __restrict__ ws_ro,
    float* __restrict__ lg32,
    unsigned char* __restrict__ chunkG,
    unsigned char* __restrict__ ftab) {
  __shared__ double region1[4224];   // 33792B: w2s f32[128][66] -> h2/lgT f64[64][66]
  __shared__ double region2[2112];   // 16896B: w3s f32[64][66] -> {F_lds, pv, pi}
  __shared__ double base1s[NH1], w1ts[NH1];  // 2048B (read 32x per wave)

  float* w2s = (float*)region1;             // [128][66] f32
  float* w3s = (float*)region2;             // [64][66] f32
  double* h2t = region1;                    // [64 t][66] f64
  double* lgT = region1;                    // [64 z][66] f64
  u8* F_lds = (u8*)region2;                 // [64 t][68] u8 = 4352B
  double* pv = (double*)((u8*)region2 + 4352);  // [8][64] f64 = 4096B
  u8* pi = (u8*)region2 + 8448;             // [8][64] u8 = 512B

  const double* __restrict__ b2dg = (const double*)(ws_ro + B2D_OFF);
  const double* __restrict__ b3dg = (const double*)(ws_ro + B3D_OFF);

  int tid = threadIdx.x, lane = tid & 63, wv = tid >> 6;
  int i15 = lane & 15, g = lane >> 4;
  int mt = wv & 3, nt0 = (wv >> 2) * 2;
  int t0 = blockIdx.x * 64;

  // ---- stage weights (f32) + f64 layer-1 constants
  for (int i = tid; i < NH1 * 64; i += 512) w2s[(i >> 6) * 66 + (i & 63)] = W2[i];
  for (int i = tid; i < NH2 * 64; i += 512) w3s[(i >> 6) * 66 + (i & 63)] = W3[i];
  if (tid < NH1) {
    base1s[tid] = ((const double*)(ws_ro + BASE1_OFF))[tid];
    w1ts[tid]   = ((const double*)(ws_ro + W1T_OFF))[tid];
  }
  double tv = (double)times[t0 + mt * 16 + i15];
  // accumulator-init biases straight from global (once per wave)
  double bi20 = b2dg[nt0 * 16 + i15], bi21 = b2dg[nt0 * 16 + 16 + i15];
  double bi30 = b3dg[nt0 * 16 + i15], bi31 = b3dg[nt0 * 16 + 16 + i15];
  __syncthreads();

  // ---- layer 2 (K=128, 32 MFMA k-steps x 2 N-tiles)
  f64x4 c0, c1;
  c0[0] = bi20; c0[1] = bi20; c0[2] = bi20; c0[3] = bi20;
  c1[0] = bi21; c1[1] = bi21; c1[2] = bi21; c1[3] = bi21;
  #pragma unroll 8
  for (int ks = 0; ks < 32; ++ks) {
    int h = ks * 4 + g;
    double a = fma(tv, w1ts[h], base1s[h]);
    a = a > 0.0 ? a : 0.0;                      // h1 = relu(...), exact f64
    double b0 = (double)w2s[h * 66 + nt0 * 16 + i15];
    double b1 = (double)w2s[h * 66 + nt0 * 16 + 16 + i15];
    c0 = __builtin_amdgcn_mfma_f64_16x16x4f64(a, b0, c0, 0, 0, 0);
    c1 = __builtin_amdgcn_mfma_f64_16x16x4f64(a, b1, c1, 0, 0, 0);
  }
  __syncthreads();  // w2s dead -> region1 becomes h2 tile
  #pragma unroll
  for (int r = 0; r < 4; ++r) {
    int t = mt * 16 + g * 4 + r;
    double v0 = c0[r] > 0.0 ? c0[r] : 0.0;      // relu(h2)
    double v1 = c1[r] > 0.0 ? c1[r] : 0.0;
    h2t[t * 66 + nt0 * 16 + i15] = v0;
    h2t[t * 66 + nt0 * 16 + 16 + i15] = v1;
  }
  __syncthreads();

  // ---- layer 3 (K=64, 16 MFMA k-steps x 2 N-tiles)
  f64x4 d0, d1;
  d0[0] = bi30; d0[1] = bi30; d0[2] = bi30; d0[3] = bi30;
  d1[0] = bi31; d1[1] = bi31; d1[2] = bi31; d1[3] = bi31;
  #pragma unroll 8
  for (int ks = 0; ks < 16; ++ks) {
    int k = ks * 4 + g;
    double a3 = h2t[(mt * 16 + i15) * 66 + k];
    double b0 = (double)w3s[k * 66 + nt0 * 16 + i15];
    double b1 = (double)w3s[k * 66 + nt0 * 16 + 16 + i15];
    d0 = __builtin_amdgcn_mfma_f64_16x16x4f64(a3, b0, d0, 0, 0, 0);
    d1 = __builtin_amdgcn_mfma_f64_16x16x4f64(a3, b1, d1, 0, 0, 0);
  }
  __syncthreads();  // h2 + w3s dead -> region1 becomes lgT, region2 free
  #pragma unroll
  for (int r = 0; r < 4; ++r) {
    int t = mt * 16 + g * 4 + r;
    int z0 = nt0 * 16 + i15, z1 = z0 + 16;
    lgT[z0 * 66 + t] = d0[r];
    lgT[z1 * 66 + t] = d1[r];
  }
  __syncthreads();

  // ---- Phase C1a + coalesced lg32 store: wave wv owns z rows [8wv,8wv+8)
  // (lane = t). Ascending z, strict > keeps first index.
  {
    int zb = wv * 8;
    double vm = lgT[zb * 66 + lane];
    int jm = zb;
    lg32[(size_t)zb * T_STEPS + t0 + lane] = (float)vm;
    #pragma unroll
    for (int zz = 1; zz < 8; ++zz) {
      double v = lgT[(zb + zz) * 66 + lane];
      lg32[(size_t)(zb + zz) * T_STEPS + t0 + lane] = (float)v;
      if (v > vm) { vm = v; jm = zb + zz; }
    }
    pv[wv * 64 + lane] = vm;
    pi[wv * 64 + lane] = (u8)jm;
  }
  __syncthreads();
  double vmax = pv[lane];
  int jmax = pi[lane];
  #pragma unroll
  for (int w = 1; w < 8; ++w) {
    double v = pv[w * 64 + lane];
    int j = pi[w * 64 + lane];
    if (v > vmax) { vmax = v; jmax = j; }  // ascending w keeps smallest z on ties
  }
  double vgap = vmax - 1.0;

  // ---- Phase C2: F[t][z] for this wave's z-slice (uniform-row scans)
  const u32* __restrict__ nbrP = (const u32*)(ws_ro + NBRP_OFF);
  const u8* __restrict__ degs = ws_ro + DEGS_OFF;
  const ull* __restrict__ adjg = (const ull*)(ws_ro + ADJ_OFF);
  #pragma unroll
  for (int zz = 0; zz < 8; ++zz) {
    int z = __builtin_amdgcn_readfirstlane(wv * 8 + zz);
    ull az = adjg[z];                                  // uniform s_load
    int nk4 = __builtin_amdgcn_readfirstlane((int)degs[z]);
    double vn = -1.0e300;
    int jn = 0;
    for (int k4 = 0; k4 < nk4; ++k4) {
      u32 w4 = nbrP[z * 16 + k4];                      // uniform s_load
      #pragma unroll
      for (int b = 0; b < 4; ++b) {
        int j = (w4 >> (b * 8)) & 63;                  // uniform
        double val = lgT[j * 66 + lane];               // uniform row read
        if (val > vn) { vn = val; jn = j; }            // ascending, strict >
      }
    }
    int bit = (int)((az >> jmax) & 1ull);
    int fnb = (vn > vgap) ? jn : ((vn < vgap) ? jmax : (jn < jmax ? jn : jmax));
    F_lds[lane * 68 + z] = (u8)(bit ? jmax : fnb);
  }
  __syncthreads();

  // ---- Phase C3: coalesced ftab write
  u32* fo = (u32*)(ftab + (size_t)t0 * 64);
  #pragma unroll
  for (int r = 0; r < 2; ++r) {
    int i = tid + r * 512;            // 1024 words = 64t x 16 words
    int t = i >> 4, z4 = (i & 15) << 2;
    fo[i] = *(const u32*)&F_lds[t * 68 + z4];
  }

  // ---- Phase C4: compose this wave's chunk table (lane = z)
  int c = blockIdx.x * 8 + wv;
  int cur = lane;
  #pragma unroll
  for (int i = 0; i < CL; ++i) cur = F_lds[(wv * 8 + i) * 68 + cur];
  chunkG[(size_t)c * 64 + lane] = (u8)cur;
}

// ---------------------------------------------------------------------------
// K3: compose SUP_L chunk tables into each super table (LDS-staged).
// ---------------------------------------------------------------------------
__global__ __launch_bounds__(256) void super_compose_kernel(
    const unsigned char* __restrict__ chunkG,
    unsigned char* __restrict__ superS) {
  __shared__ u8 g[4][SUP_L * 64];  // 16KB
  int tid = threadIdx.x, lane = tid & 63, wv = tid >> 6;
  int k = blockIdx.x * 4 + wv;
  const u32* src = (const u32*)(chunkG + (size_t)k * SUP_L * 64);
  u32* dst = (u32*)g[wv];
  #pragma unroll 4
  for (int i = lane; i < SUP_L * 16; i += 64) dst[i] = src[i];
  // wave-private LDS region; compiler orders the dependent reads
  int cur = lane;
  #pragma unroll 8
  for (int c = 0; c < SUP_L; ++c) {
    int gg = g[wv][c * 64 + lane];
    cur = __shfl(gg, cur, 64);
  }
  superS[(size_t)k * 64 + lane] = (u8)cur;
}

// ---------------------------------------------------------------------------
// K4 (fused): per-chunk start states + finalize. 1024 blocks x 256 threads;
// block b owns 8 chunks [8b, 8b+8), all inside super k = b/8. lg32/ftab are
// prefetched into regs/LDS BEFORE the state walks so HBM/L2 latency hides.
// region is NSUPER*64 = 8KB: holds the full ssup stage (8KB), then the
// super-k chunkG tile (4KB) overwrites its low half. (Round-11 bug: region
// was SUP_L*64 = 4KB -> ssup stage overflowed into adjs/fstage.)
// ---------------------------------------------------------------------------
__global__ __launch_bounds__(256) void states_finalize_kernel(
    const float* __restrict__ lg32, const unsigned char* __restrict__ ws_ro,
    const unsigned char* __restrict__ chunkG,
    const unsigned char* __restrict__ superS,
    const unsigned char* __restrict__ ftab,
    float* __restrict__ out) {
  __shared__ u8 region[NSUPER * 64];    // 8KB: ssup, then chunkG tile (4KB)
  __shared__ ull adjs[64];
  __shared__ u8 fstage[4][2][CL * 64];  // 4KB
  int tid = threadIdx.x, lane = tid & 63, wv = tid >> 6;
  int b = blockIdx.x;
  int k = b >> 3;          // super index
  int myc = b * 8 + wv * 2;  // wave's first chunk

  if (tid < 64) adjs[tid] = ((const ull*)(ws_ro + ADJ_OFF))[tid];
  // stage ssup (8KB)
  for (int i = tid; i < NSUPER * 16; i += 256)
    ((u32*)region)[i] = ((const u32*)superS)[i];
  // prefetch logits (64B contiguous per lane across the wave's 2 chunks)
  float lgv[2][CL];
  #pragma unroll
  for (int cc = 0; cc < 2; ++cc)
    #pragma unroll
    for (int i = 0; i < CL; ++i)
      lgv[cc][i] = lg32[(size_t)lane * T_STEPS + (myc + cc) * CL + i];
  // prefetch F tables
  #pragma unroll
  for (int cc = 0; cc < 2; ++cc)
    for (int i = lane; i < CL * 16; i += 64)
      ((u32*)fstage[wv][cc])[i] =
          ((const u32*)(ftab + (size_t)(myc + cc) * CL * 64))[i];
  __syncthreads();

  // super prefix walk (uniform across all threads)
  int s = 0;
  for (int i = 0; i < k; ++i) s = region[i * 64 + s];
  __syncthreads();  // everyone done reading ssup
  // stage super k's chunkG tile (4KB, overwrites low half of region)
  {
    const u32* cg = (const u32*)(chunkG + (size_t)k * SUP_L * 64);
    for (int i = tid; i < SUP_L * 16; i += 256) ((u32*)region)[i] = cg[i];
  }
  __syncthreads();
  // walk to this block's chunk range, then through it capturing entries
  int lc0 = (b & 7) * 8;
  for (int c = 0; c < lc0; ++c) s = region[c * 64 + s];
  int e0 = 0, e1 = 0;
  #pragma unroll
  for (int j = 0; j < 8; ++j) {
    if (j == wv * 2) e0 = s;
    if (j == wv * 2 + 1) e1 = s;
    s = region[(lc0 + j) * 64 + s];
  }

  // finalize the wave's 2 chunks
  #pragma unroll
  for (int cc = 0; cc < 2; ++cc) {
    int st = cc ? e1 : e0;
    size_t tb = (size_t)(myc + cc) * CL * 64;
    #pragma unroll
    for (int i = 0; i < CL; ++i) {
      int bit = (int)((adjs[st] >> lane) & 1ull);
      float v = lgv[cc][i];
      out[tb + i * 64 + lane] = bit ? v : v - 1.0f;
      st = fstage[wv][cc][i * 64 + st];  // uniform broadcast read
    }
  }
}

// ---------------------------------------------------------------------------
extern "C" void kernel_launch(void* const* d_in, const int* in_sizes, int n_in,
                              void* d_out, int out_size, void* d_ws, size_t ws_size,
                              hipStream_t stream) {
  const float* pa    = (const float*)d_in[0];
  const float* times = (const float*)d_in[1];
  // d_in[2] zone_features: unused by the reference
  const int*   edges = (const int*)d_in[3];
  const float* W1    = (const float*)d_in[4];
  const float* b1    = (const float*)d_in[5];
  const float* W2    = (const float*)d_in[6];
  const float* b2    = (const float*)d_in[7];
  const float* W3    = (const float*)d_in[8];
  const float* b3    = (const float*)d_in[9];

  unsigned char* ws = (unsigned char*)d_ws;
  float* lg32 = (float*)(ws + LG32_OFF);
  unsigned char* ftab = ws + FTAB_OFF;
  unsigned char* chunkG = ws + CHUNKG_WS;
  unsigned char* superS = ws + SUPERS_WS;

  hipLaunchKernelGGL(prep_kernel, dim3(1), dim3(512), 0, stream,
                     pa, edges, W1, b1, b2, b3, ws);
  hipLaunchKernelGGL(mlp_tables_kernel, dim3(T_STEPS / 64), dim3(512), 0, stream,
                     times, W2, W3, ws, lg32, chunkG, ftab);
  hipLaunchKernelGGL(super_compose_kernel, dim3(NSUPER / 4), dim3(256), 0, stream,
                     chunkG, superS);
  hipLaunchKernelGGL(states_finalize_kernel, dim3(NCHUNK / 8), dim3(256), 0, stream,
                     lg32, ws, chunkG, superS, ftab, (float*)d_out);
}

// Round 13
// 78.502 us; speedup vs baseline: 3.7054x; 1.0689x over previous
//
#include <hip/hip_runtime.h>

#define T_STEPS 65536
#define NZ 64
#define NH1 128
#define NH2 64
#define NEDGE 512
#define NCHUNK 8192
#define CL 8            // timesteps per chunk (T_STEPS / NCHUNK)
#define NSUPER 128
#define SUP_L 64        // chunks per super (NCHUNK / NSUPER)

// ---- ws layout (bytes). Total ~21.2MB (proven ws >= 33.7MB in rounds 2-6)
#define ADJ_OFF        0          // 64 * u64
#define BASE1_OFF      512        // 128 * f64
#define W1T_OFF        1536      // 128 * f64
#define NBRP_OFF       2560      // 64 z * 16 u32 words (4 packed u8 ids each) = 4096
#define DEGS_OFF       6656      // 64 u8: per-z u32-word count (ceil(deg/4))
#define B2D_OFF        139264    // 64 f64
#define B3D_OFF        139776    // 64 f64
#define LG32_OFF       140288    // 64*T f32 (z-major: lg32[z*T + t]) = 16MB
#define FTAB_OFF       (LG32_OFF + (size_t)T_STEPS * NZ * 4)   // T*64 u8 = 4MB
#define CHUNKG_WS      (FTAB_OFF + (size_t)T_STEPS * NZ)       // 512KB
#define SUPERS_WS      (CHUNKG_WS + (size_t)NCHUNK * 64)       // 8KB

typedef unsigned long long ull;
typedef unsigned int u32;
typedef unsigned char u8;
typedef double f64x4 __attribute__((ext_vector_type(4)));

// ---------------------------------------------------------------------------
// K1: 2 blocks. Block 0: adjacency bitmasks + packed neighbor lists.
// Block 1: base1/w1t matvec + f64 biases. Disjoint ws regions, no deps.
// ---------------------------------------------------------------------------
__global__ void prep_kernel(const float* __restrict__ pa,
                            const int* __restrict__ edges,
                            const float* __restrict__ W1,
                            const float* __restrict__ b1,
                            const float* __restrict__ b2,
                            const float* __restrict__ b3,
                            unsigned char* ws) {
  int tid = threadIdx.x;
  if (blockIdx.x == 0) {
    ull* adj = (ull*)(ws + ADJ_OFF);
    if (tid < NZ) adj[tid] = 0ull;
    __syncthreads();
    if (tid < NEDGE) {
      int e0 = edges[tid];
      int e1 = edges[NEDGE + tid];
      atomicOr(&adj[e0], 1ull << e1);
      atomicOr(&adj[e1], 1ull << e0);
    }
    if (tid < NZ) atomicOr(&adj[tid], 1ull << tid);  // self loops
    __syncthreads();
    if (tid < NZ) {
      ull m = adj[tid];
      u32 wbuf[16];
      #pragma unroll
      for (int i = 0; i < 16; ++i) wbuf[i] = 0u;
      int deg = 0, jfirst = 0;
      while (m) {
        int j = __builtin_ctzll(m);
        m &= m - 1;
        if (deg == 0) jfirst = j;
        wbuf[deg >> 2] |= (u32)j << ((deg & 3) * 8);
        ++deg;
      }
      int padded = (deg + 3) & ~3;
      for (int k = deg; k < padded; ++k)
        wbuf[k >> 2] |= (u32)jfirst << ((k & 3) * 8);
      u32* np = (u32*)(ws + NBRP_OFF) + tid * 16;
      #pragma unroll
      for (int i = 0; i < 16; ++i) np[i] = wbuf[i];
      (ws + DEGS_OFF)[tid] = (u8)(padded >> 2);
    }
  } else {
    double* base1 = (double*)(ws + BASE1_OFF);
    double* w1t   = (double*)(ws + W1T_OFF);
    double* b2d = (double*)(ws + B2D_OFF);
    double* b3d = (double*)(ws + B3D_OFF);
    if (tid < NH1) {
      double acc = (double)b1[tid];
      for (int d = 0; d < 64; ++d)
        acc += (double)pa[d] * (double)W1[d * NH1 + tid];
      base1[tid] = acc;
      w1t[tid] = (double)W1[64 * NH1 + tid];
    }
    if (tid < NH2) b2d[tid] = (double)b2[tid];
    if (tid < NZ)  b3d[tid] = (double)b3[tid];
  }
}

// ---------------------------------------------------------------------------
// K2 (fused): MFMA-f64 MLP + per-chunk transition tables.
// 512 threads = 8 waves; block owns 64 timesteps.
// LDS = 38656B -> 4 blocks/CU (32 waves/CU, HW max):
//  - W3 is read straight from global in layer 3 (16KB, L1-resident; per-lane
//    addresses form 4x64B contiguous segments) -> no w3s stage (-16.9KB).
//  - region2 (4864B) is overlaid, barrier-separated:
//      [layers]  base1s[128] f64 | w1ts[128] f64          (2KB)
//      [C1a/mrg] pv[8][64] f64 (0..4096) | pi (4352..4864)
//      [C2+]     F_lds[64][68] u8 (0..4352) | pi intact
// ---------------------------------------------------------------------------
__global__ __launch_bounds__(512, 8) void mlp_tables_kernel(
    const float* __restrict__ times,
    const float* __restrict__ W2,
    const float* __restrict__ W3,
    const unsigned char* __restrict__ ws_ro,
    float* __restrict__ lg32,
    unsigned char* __restrict__ chunkG,
    unsigned char* __restrict__ ftab) {
  __shared__ double region1[4224];   // 33792B: w2s f32[128][66] -> h2t/lgT f64[64][66]
  __shared__ double region2[608];    // 4864B: overlaid (see header)

  float* w2s = (float*)region1;             // [128][66] f32
  double* h2t = region1;                    // [64 t][66] f64
  double* lgT = region1;                    // [64 z][66] f64
  double* base1s = region2;                 // [128] f64
  double* w1ts = region2 + 128;             // [128] f64
  double* pv = region2;                     // [8][64] f64 at [0,4096)
  u8* pi = (u8*)region2 + 4352;             // [8][64] u8 at [4352,4864)
  u8* F_lds = (u8*)region2;                 // [64][68] u8 at [0,4352)

  const double* __restrict__ b2dg = (const double*)(ws_ro + B2D_OFF);
  const double* __restrict__ b3dg = (const double*)(ws_ro + B3D_OFF);

  int tid = threadIdx.x, lane = tid & 63, wv = tid >> 6;
  int i15 = lane & 15, g = lane >> 4;
  int mt = wv & 3, nt0 = (wv >> 2) * 2;
  int t0 = blockIdx.x * 64;

  // ---- stage W2 (f32) + f64 layer-1 constants
  for (int i = tid; i < NH1 * 64; i += 512) w2s[(i >> 6) * 66 + (i & 63)] = W2[i];
  if (tid < NH1) {
    base1s[tid] = ((const double*)(ws_ro + BASE1_OFF))[tid];
    w1ts[tid]   = ((const double*)(ws_ro + W1T_OFF))[tid];
  }
  double tv = (double)times[t0 + mt * 16 + i15];
  // accumulator-init biases straight from global (once per wave)
  double bi20 = b2dg[nt0 * 16 + i15], bi21 = b2dg[nt0 * 16 + 16 + i15];
  double bi30 = b3dg[nt0 * 16 + i15], bi31 = b3dg[nt0 * 16 + 16 + i15];
  __syncthreads();

  // ---- layer 2 (K=128, 32 MFMA k-steps x 2 N-tiles)
  f64x4 c0, c1;
  c0[0] = bi20; c0[1] = bi20; c0[2] = bi20; c0[3] = bi20;
  c1[0] = bi21; c1[1] = bi21; c1[2] = bi21; c1[3] = bi21;
  #pragma unroll 8
  for (int ks = 0; ks < 32; ++ks) {
    int h = ks * 4 + g;
    double a = fma(tv, w1ts[h], base1s[h]);
    a = a > 0.0 ? a : 0.0;                      // h1 = relu(...), exact f64
    double b0 = (double)w2s[h * 66 + nt0 * 16 + i15];
    double b1 = (double)w2s[h * 66 + nt0 * 16 + 16 + i15];
    c0 = __builtin_amdgcn_mfma_f64_16x16x4f64(a, b0, c0, 0, 0, 0);
    c1 = __builtin_amdgcn_mfma_f64_16x16x4f64(a, b1, c1, 0, 0, 0);
  }
  __syncthreads();  // w2s + base1s/w1ts dead -> region1 becomes h2 tile
  #pragma unroll
  for (int r = 0; r < 4; ++r) {
    int t = mt * 16 + g * 4 + r;
    double v0 = c0[r] > 0.0 ? c0[r] : 0.0;      // relu(h2)
    double v1 = c1[r] > 0.0 ? c1[r] : 0.0;
    h2t[t * 66 + nt0 * 16 + i15] = v0;
    h2t[t * 66 + nt0 * 16 + 16 + i15] = v1;
  }
  __syncthreads();

  // ---- layer 3 (K=64, 16 MFMA k-steps x 2 N-tiles); W3 from global (L1)
  f64x4 d0, d1;
  d0[0] = bi30; d0[1] = bi30; d0[2] = bi30; d0[3] = bi30;
  d1[0] = bi31; d1[1] = bi31; d1[2] = bi31; d1[3] = bi31;
  #pragma unroll 8
  for (int ks = 0; ks < 16; ++ks) {
    int k = ks * 4 + g;
    double a3 = h2t[(mt * 16 + i15) * 66 + k];
    double b0 = (double)W3[k * 64 + nt0 * 16 + i15];
    double b1 = (double)W3[k * 64 + nt0 * 16 + 16 + i15];
    d0 = __builtin_amdgcn_mfma_f64_16x16x4f64(a3, b0, d0, 0, 0, 0);
    d1 = __builtin_amdgcn_mfma_f64_16x16x4f64(a3, b1, d1, 0, 0, 0);
  }
  __syncthreads();  // h2 dead -> region1 becomes lgT
  #pragma unroll
  for (int r = 0; r < 4; ++r) {
    int t = mt * 16 + g * 4 + r;
    int z0 = nt0 * 16 + i15, z1 = z0 + 16;
    lgT[z0 * 66 + t] = d0[r];
    lgT[z1 * 66 + t] = d1[r];
  }
  __syncthreads();

  // ---- Phase C1a + coalesced lg32 store: wave wv owns z rows [8wv,8wv+8)
  // (lane = t). Ascending z, strict > keeps first index.
  {
    int zb = wv * 8;
    double vm = lgT[zb * 66 + lane];
    int jm = zb;
    lg32[(size_t)zb * T_STEPS + t0 + lane] = (float)vm;
    #pragma unroll
    for (int zz = 1; zz < 8; ++zz) {
      double v = lgT[(zb + zz) * 66 + lane];
      lg32[(size_t)(zb + zz) * T_STEPS + t0 + lane] = (float)v;
      if (v > vm) { vm = v; jm = zb + zz; }
    }
    pv[wv * 64 + lane] = vm;
    pi[wv * 64 + lane] = (u8)jm;
  }
  __syncthreads();
  double vmax = pv[lane];
  int jmax = pi[lane];
  #pragma unroll
  for (int w = 1; w < 8; ++w) {
    double v = pv[w * 64 + lane];
    int j = pi[w * 64 + lane];
    if (v > vmax) { vmax = v; jmax = j; }  // ascending w keeps smallest z on ties
  }
  double vgap = vmax - 1.0;
  __syncthreads();  // pv dead before F_lds overlay-writes

  // ---- Phase C2: F[t][z] for this wave's z-slice (uniform-row scans)
  const u32* __restrict__ nbrP = (const u32*)(ws_ro + NBRP_OFF);
  const u8* __restrict__ degs = ws_ro + DEGS_OFF;
  const ull* __restrict__ adjg = (const ull*)(ws_ro + ADJ_OFF);
  #pragma unroll
  for (int zz = 0; zz < 8; ++zz) {
    int z = __builtin_amdgcn_readfirstlane(wv * 8 + zz);
    ull az = adjg[z];                                  // uniform s_load
    int nk4 = __builtin_amdgcn_readfirstlane((int)degs[z]);
    double vn = -1.0e300;
    int jn = 0;
    for (int k4 = 0; k4 < nk4; ++k4) {
      u32 w4 = nbrP[z * 16 + k4];                      // uniform s_load
      #pragma unroll
      for (int b = 0; b < 4; ++b) {
        int j = (w4 >> (b * 8)) & 63;                  // uniform
        double val = lgT[j * 66 + lane];               // uniform row read
        if (val > vn) { vn = val; jn = j; }            // ascending, strict >
      }
    }
    int bit = (int)((az >> jmax) & 1ull);
    int fnb = (vn > vgap) ? jn : ((vn < vgap) ? jmax : (jn < jmax ? jn : jmax));
    F_lds[lane * 68 + z] = (u8)(bit ? jmax : fnb);
  }
  __syncthreads();

  // ---- Phase C3: coalesced ftab write
  u32* fo = (u32*)(ftab + (size_t)t0 * 64);
  #pragma unroll
  for (int r = 0; r < 2; ++r) {
    int i = tid + r * 512;            // 1024 words = 64t x 16 words
    int t = i >> 4, z4 = (i & 15) << 2;
    fo[i] = *(const u32*)&F_lds[t * 68 + z4];
  }

  // ---- Phase C4: compose this wave's chunk table (lane = z)
  int c = blockIdx.x * 8 + wv;
  int cur = lane;
  #pragma unroll
  for (int i = 0; i < CL; ++i) cur = F_lds[(wv * 8 + i) * 68 + cur];
  chunkG[(size_t)c * 64 + lane] = (u8)cur;
}

// ---------------------------------------------------------------------------
// K3: compose SUP_L chunk tables into each super table (LDS-staged).
// ---------------------------------------------------------------------------
__global__ __launch_bounds__(256) void super_compose_kernel(
    const unsigned char* __restrict__ chunkG,
    unsigned char* __restrict__ superS) {
  __shared__ u8 g[4][SUP_L * 64];  // 16KB
  int tid = threadIdx.x, lane = tid & 63, wv = tid >> 6;
  int k = blockIdx.x * 4 + wv;
  const u32* src = (const u32*)(chunkG + (size_t)k * SUP_L * 64);
  u32* dst = (u32*)g[wv];
  #pragma unroll 4
  for (int i = lane; i < SUP_L * 16; i += 64) dst[i] = src[i];
  // wave-private LDS region; compiler orders the dependent reads
  int cur = lane;
  #pragma unroll 8
  for (int c = 0; c < SUP_L; ++c) {
    int gg = g[wv][c * 64 + lane];
    cur = __shfl(gg, cur, 64);
  }
  superS[(size_t)k * 64 + lane] = (u8)cur;
}

// ---------------------------------------------------------------------------
// K4 (fused): per-chunk start states + finalize. 1024 blocks x 256 threads;
// block b owns 8 chunks [8b, 8b+8), all inside super k = b/8. lg32/ftab are
// prefetched into regs/LDS BEFORE the state walks so HBM/L2 latency hides.
// region is NSUPER*64 = 8KB: full ssup stage, then the 4KB chunkG tile
// overwrites its low half.
// ---------------------------------------------------------------------------
__global__ __launch_bounds__(256) void states_finalize_kernel(
    const float* __restrict__ lg32, const unsigned char* __restrict__ ws_ro,
    const unsigned char* __restrict__ chunkG,
    const unsigned char* __restrict__ superS,
    const unsigned char* __restrict__ ftab,
    float* __restrict__ out) {
  __shared__ u8 region[NSUPER * 64];    // 8KB: ssup, then chunkG tile (4KB)
  __shared__ ull adjs[64];
  __shared__ u8 fstage[4][2][CL * 64];  // 4KB
  int tid = threadIdx.x, lane = tid & 63, wv = tid >> 6;
  int b = blockIdx.x;
  int k = b >> 3;          // super index
  int myc = b * 8 + wv * 2;  // wave's first chunk

  if (tid < 64) adjs[tid] = ((const ull*)(ws_ro + ADJ_OFF))[tid];
  // stage ssup (8KB)
  for (int i = tid; i < NSUPER * 16; i += 256)
    ((u32*)region)[i] = ((const u32*)superS)[i];
  // prefetch logits (64B contiguous per lane across the wave's 2 chunks)
  float lgv[2][CL];
  #pragma unroll
  for (int cc = 0; cc < 2; ++cc)
    #pragma unroll
    for (int i = 0; i < CL; ++i)
      lgv[cc][i] = lg32[(size_t)lane * T_STEPS + (myc + cc) * CL + i];
  // prefetch F tables
  #pragma unroll
  for (int cc = 0; cc < 2; ++cc)
    for (int i = lane; i < CL * 16; i += 64)
      ((u32*)fstage[wv][cc])[i] =
          ((const u32*)(ftab + (size_t)(myc + cc) * CL * 64))[i];
  __syncthreads();

  // super prefix walk (uniform across all threads)
  int s = 0;
  for (int i = 0; i < k; ++i) s = region[i * 64 + s];
  __syncthreads();  // everyone done reading ssup
  // stage super k's chunkG tile (4KB, overwrites low half of region)
  {
    const u32* cg = (const u32*)(chunkG + (size_t)k * SUP_L * 64);
    for (int i = tid; i < SUP_L * 16; i += 256) ((u32*)region)[i] = cg[i];
  }
  __syncthreads();
  // walk to this block's chunk range, then through it capturing entries
  int lc0 = (b & 7) * 8;
  for (int c = 0; c < lc0; ++c) s = region[c * 64 + s];
  int e0 = 0, e1 = 0;
  #pragma unroll
  for (int j = 0; j < 8; ++j) {
    if (j == wv * 2) e0 = s;
    if (j == wv * 2 + 1) e1 = s;
    s = region[(lc0 + j) * 64 + s];
  }

  // finalize the wave's 2 chunks
  #pragma unroll
  for (int cc = 0; cc < 2; ++cc) {
    int st = cc ? e1 : e0;
    size_t tb = (size_t)(myc + cc) * CL * 64;
    #pragma unroll
    for (int i = 0; i < CL; ++i) {
      int bit = (int)((adjs[st] >> lane) & 1ull);
      float v = lgv[cc][i];
      out[tb + i * 64 + lane] = bit ? v : v - 1.0f;
      st = fstage[wv][cc][i * 64 + st];  // uniform broadcast read
    }
  }
}

// ---------------------------------------------------------------------------
extern "C" void kernel_launch(void* const* d_in, const int* in_sizes, int n_in,
                              void* d_out, int out_size, void* d_ws, size_t ws_size,
                              hipStream_t stream) {
  const float* pa    = (const float*)d_in[0];
  const float* times = (const float*)d_in[1];
  // d_in[2] zone_features: unused by the reference
  const int*   edges = (const int*)d_in[3];
  const float* W1    = (const float*)d_in[4];
  const float* b1    = (const float*)d_in[5];
  const float* W2    = (const float*)d_in[6];
  const float* b2    = (const float*)d_in[7];
  const float* W3    = (const float*)d_in[8];
  const float* b3    = (const float*)d_in[9];

  unsigned char* ws = (unsigned char*)d_ws;
  float* lg32 = (float*)(ws + LG32_OFF);
  unsigned char* ftab = ws + FTAB_OFF;
  unsigned char* chunkG = ws + CHUNKG_WS;
  unsigned char* superS = ws + SUPERS_WS;

  hipLaunchKernelGGL(prep_kernel, dim3(2), dim3(512), 0, stream,
                     pa, edges, W1, b1, b2, b3, ws);
  hipLaunchKernelGGL(mlp_tables_kernel, dim3(T_STEPS / 64), dim3(512), 0, stream,
                     times, W2, W3, ws, lg32, chunkG, ftab);
  hipLaunchKernelGGL(super_compose_kernel, dim3(NSUPER / 4), dim3(256), 0, stream,
                     chunkG, superS);
  hipLaunchKernelGGL(states_finalize_kernel, dim3(NCHUNK / 8), dim3(256), 0, stream,
                     lg32, ws, chunkG, superS, ftab, (float*)d_out);
}